// Round 2
// baseline (10663.861 us; speedup 1.0000x reference)
//
#include <hip/hip_runtime.h>

// ---------------------------------------------------------------------------
// BiDAF block: B=32, CLEN=384, QLEN=64, H=768
// Workspace layout (~228MB):
//   [0, 75.5MB)    g  (later: mA @0, mB @37.7MB, m2 @0)
//   [75.5, 226.5)  xg (attention temps alias the front of this region)
//   [226.5, +)     tail scalars + E exchange buffer (786KB)
// R5: k_lstm exchange = tag-in-data dwords {tag:16|bf16 h:16} in LLC-resident
// E buffer, parity double-buffered. Consumers poll data tags directly.
// R7: latency hiding — the 4 independent recurrences (dir x batch-group) are
// interleaved inside one block (grid 48 = col-slices of 16, 512 threads,
// wave = gate x dir, whh in VGPR 96/wave). Each phase checks poll loads that
// were ISSUED TWO PHASES EARLIER, so the E store->LLC->load round trip is
// overlapped with the other chains' MFMA+gate compute. Intra-phase barriers
// are raw s_barrier + lgkmcnt(0) (no vmcnt drain) so polls stay in flight.
// ---------------------------------------------------------------------------

typedef __bf16 bf16_t;
typedef __bf16 bf16x4 __attribute__((ext_vector_type(4)));
typedef __bf16 bf16x8 __attribute__((ext_vector_type(8)));
typedef float  f32x4  __attribute__((ext_vector_type(4)));
typedef unsigned long long ull;

#define TT 384

__device__ __forceinline__ void gload_lds16(const void* g, void* l) {
  __builtin_amdgcn_global_load_lds((const __attribute__((address_space(1))) void*)g,
                                   (__attribute__((address_space(3))) void*)l, 16, 0, 0);
}

// workgroup barrier ordering LDS only: does NOT drain vmcnt, so global poll
// loads issued earlier stay in flight across it (unlike __syncthreads()).
__device__ __forceinline__ void wg_barrier_lds() {
  asm volatile("s_waitcnt lgkmcnt(0)" ::: "memory");
  __builtin_amdgcn_s_barrier();
  asm volatile("" ::: "memory");
}

// set all E tags to 0xFFFF (never matches a wanted tag in [0,1152))
__global__ void k_zeroE(unsigned* p) {
  int i = blockIdx.x * 256 + threadIdx.x;
  __hip_atomic_store(p + i, 0xFFFF0000u, __ATOMIC_RELAXED, __HIP_MEMORY_SCOPE_AGENT);
}

// ---------------------------------------------------------------------------
// GEMM: C[M,N] = A[M,K] * B[N,K]^T, A bf16 K-contig (global_load_lds).
// BSRC=0: B bf16 via global_load_lds (Bv + bz*sBb). BSRC=1: B fp32 from
// Bv (rows < nsplit) / Bv2 (rows >= nsplit), converted during staging.
// BM=128, BK=32, 256 threads = 4 waves (2x2), wave tile 64 x (BN/2).
// EPI=0: bf16 out. EPI=1: f32 out + rowb[bz*M+row] + colb[bz*N+col] + *sb.
// ---------------------------------------------------------------------------
template<int BN, int EPI, int BSRC>
__global__ __launch_bounds__(256) void k_gemm(
    const bf16_t* __restrict__ A, const void* __restrict__ Bv, const void* __restrict__ Bv2,
    int nsplit, void* __restrict__ Cv,
    int M, int N, int K, long sAb, long sBb, long sCb,
    const float* __restrict__ rowb, const float* __restrict__ colb,
    const float* __restrict__ sb)
{
  constexpr int BM = 128, BK = 32;
  constexpr int NT = BN / 32;          // 16-wide N tiles per wave
  __shared__ bf16_t sA[BM * BK];
  __shared__ bf16_t sB[BN * BK];
  const int t    = threadIdx.x;
  const int lane = t & 63;
  const int wm   = (t >> 6) >> 1, wn = (t >> 6) & 1;
  const long bz  = blockIdx.z;
  const int nbase = blockIdx.y * BN;
  const bf16_t* Ab = A + bz * sAb + (long)blockIdx.x * BM * K;
  const bf16_t* Bb = nullptr;
  const float*  Bf = nullptr;
  if constexpr (BSRC == 0)
    Bb = (const bf16_t*)Bv + bz * sBb + (long)nbase * K;
  else
    Bf = (nbase < nsplit) ? ((const float*)Bv  + (long)nbase * K)
                          : ((const float*)Bv2 + (long)(nbase - nsplit) * K);

  const int r4 = t >> 2;                          // staging row 0..63
  const int kq = (t & 3) ^ ((r4 >> 1) & 3);       // XOR-swizzled source k-quad

  f32x4 acc[4][NT];
  #pragma unroll
  for (int i = 0; i < 4; i++)
    #pragma unroll
    for (int j = 0; j < NT; j++) acc[i][j] = (f32x4){0.f, 0.f, 0.f, 0.f};

  const int mrow = lane & 15;
  const int fq   = lane >> 4;
  const int aswz = (fq ^ ((mrow >> 1) & 3)) * 8;  // swizzled frag k-offset (elems)

  for (int k0 = 0; k0 < K; k0 += BK) {
    __syncthreads();
    gload_lds16(Ab + (long)r4 * K + k0 + kq * 8,        (char*)sA + t * 16);
    gload_lds16(Ab + (long)(64 + r4) * K + k0 + kq * 8, (char*)sA + 4096 + t * 16);
    if constexpr (BSRC == 0) {
      gload_lds16(Bb + (long)r4 * K + k0 + kq * 8,        (char*)sB + t * 16);
      if constexpr (BN == 128)
        gload_lds16(Bb + (long)(64 + r4) * K + k0 + kq * 8, (char*)sB + 4096 + t * 16);
    } else {
      {
        f32x4 b0 = *(const f32x4*)(Bf + (long)r4 * K + k0 + kq * 8);
        f32x4 b1 = *(const f32x4*)(Bf + (long)r4 * K + k0 + kq * 8 + 4);
        bf16x8 bb;
        #pragma unroll
        for (int e = 0; e < 4; e++) { bb[e] = (bf16_t)b0[e]; bb[e + 4] = (bf16_t)b1[e]; }
        *(bf16x8*)((char*)sB + t * 16) = bb;
      }
      if constexpr (BN == 128) {
        f32x4 b0 = *(const f32x4*)(Bf + (long)(64 + r4) * K + k0 + kq * 8);
        f32x4 b1 = *(const f32x4*)(Bf + (long)(64 + r4) * K + k0 + kq * 8 + 4);
        bf16x8 bb;
        #pragma unroll
        for (int e = 0; e < 4; e++) { bb[e] = (bf16_t)b0[e]; bb[e + 4] = (bf16_t)b1[e]; }
        *(bf16x8*)((char*)sB + 4096 + t * 16) = bb;
      }
    }
    __syncthreads();

    bf16x8 af[4], bv[NT];
    #pragma unroll
    for (int mt = 0; mt < 4; mt++)
      af[mt] = *(const bf16x8*)(sA + (wm * 64 + mt * 16 + mrow) * 32 + aswz);
    #pragma unroll
    for (int nt = 0; nt < NT; nt++)
      bv[nt] = *(const bf16x8*)(sB + (wn * (BN / 2) + nt * 16 + mrow) * 32 + aswz);
    #pragma unroll
    for (int mt = 0; mt < 4; mt++)
      #pragma unroll
      for (int nt = 0; nt < NT; nt++)
        acc[mt][nt] = __builtin_amdgcn_mfma_f32_16x16x32_bf16(af[mt], bv[nt], acc[mt][nt], 0, 0, 0);
  }

  const int rbase = (lane >> 4) * 4;
  #pragma unroll
  for (int mt = 0; mt < 4; mt++)
    #pragma unroll
    for (int nt = 0; nt < NT; nt++)
      #pragma unroll
      for (int r = 0; r < 4; r++) {
        int grow = blockIdx.x * BM + wm * 64 + mt * 16 + rbase + r;
        int gcol = nbase + wn * (BN / 2) + nt * 16 + (lane & 15);
        if constexpr (EPI == 0) {
          ((bf16_t*)Cv)[bz * sCb + (long)grow * N + gcol] = (bf16_t)acc[mt][nt][r];
        } else {
          ((float*)Cv)[bz * sCb + (long)grow * N + gcol] =
              acc[mt][nt][r] + rowb[bz * M + grow] + colb[bz * N + gcol] + sb[0];
        }
      }
}

// ---------------------------------------------------------------------------
// Recurrent biLSTM stage, 4-chain interleaved. grid = 48 (col-slices of 16),
// 512 threads = 8 waves, wave w: gate g = w&3, dir wd = w>>2. whh tile of
// this wave's (dir,gate,16 cols) lives in VGPRs (24 x bf16x8 = 96 VGPR).
// Chains C0=(d0,b0) C1=(d0,b1) C2=(d1,b0) C3=(d1,b1) advance once per outer
// iteration; chain i's poll loads are issued 2 phases before their check so
// the LLC round trip overlaps the other chains' compute. qvA serves C0/C2,
// qvB serves C1/C3 (alternating).
// E dwords {tag:16|bf16 h:16}, parity double-buffered, relaxed AGENT atomics.
// xg: [B*T, 6144] bf16 (fwd 4H | bwd 4H, gate order i,f,g,o).
// mout: [B, T, 2H] bf16 (fwd | bwd) — plain stores, for downstream kernels.
// ---------------------------------------------------------------------------

#define LSTM_PHASE(D, BGc, CST, QV, ID, IB, IPAR)                                  \
  {                                                                                \
    const int tc = (D) ? (TT - 1 - s) : s;                                         \
    float xv0 = 0.f, xv1 = 0.f, xv2 = 0.f, xv3 = 0.f;                              \
    if (t < 256) {                                                                 \
      long xr = ((long)((BGc) * 16 + b16e) * TT + tc) * 6144 + (D) * 3072 + j0 + jje; \
      xv0 = (float)xg[xr];        xv1 = (float)xg[xr + 768];                       \
      xv2 = (float)xg[xr + 1536]; xv3 = (float)xg[xr + 2304];                      \
    }                                                                              \
    if (s == 0) {                                                                  \
      if ((D) == 0 && (BGc) == 0) {                                                \
        for (int e = t; e < 1552; e += 512)                                        \
          *(f32x4*)((char*)sH + e * 16) = (f32x4){0.f, 0.f, 0.f, 0.f};             \
      }                                                                            \
    } else {                                                                       \
      const unsigned want = (unsigned)(tagbase + s - 1);                           \
      const ull* rsrc = (const ull*)E + ((long)(((s - 1) & 1) * 2 + (D)) * 32 + (BGc) * 16) * 384; \
      for (;;) {                                                                   \
        unsigned bad = 0;                                                          \
        _Pragma("unroll")                                                          \
        for (int i = 0; i < 12; i++) {                                             \
          unsigned lo = (unsigned)QV[i], hi = (unsigned)(QV[i] >> 32);             \
          if ((lo >> 16) != want || (hi >> 16) != want) bad |= 1u << i;            \
        }                                                                          \
        if (!bad) break;                                                           \
        _Pragma("unroll")                                                          \
        for (int i = 0; i < 12; i++)                                               \
          if (bad & (1u << i))                                                     \
            QV[i] = __hip_atomic_load(rsrc + i * 512 + t, __ATOMIC_RELAXED, __HIP_MEMORY_SCOPE_AGENT); \
      }                                                                            \
      _Pragma("unroll")                                                            \
      for (int i = 0; i < 12; i++) {                                               \
        ushort2 hh;                                                                \
        hh.x = (unsigned short)QV[i];                                              \
        hh.y = (unsigned short)(QV[i] >> 32);                                      \
        *(ushort2*)((char*)sH + soff[i]) = hh;                                     \
      }                                                                            \
    }                                                                              \
    {                                                                              \
      const ull* isrc = (const ull*)E + ((long)((IPAR) * 2 + (ID)) * 32 + (IB) * 16) * 384; \
      _Pragma("unroll")                                                            \
      for (int i = 0; i < 12; i++)                                                 \
        QV[i] = __hip_atomic_load(isrc + i * 512 + t, __ATOMIC_RELAXED, __HIP_MEMORY_SCOPE_AGENT); \
    }                                                                              \
    wg_barrier_lds();                                                              \
    if (wd == (D)) {                                                               \
      f32x4 a0 = (f32x4){0.f, 0.f, 0.f, 0.f};                                      \
      f32x4 a1 = (f32x4){0.f, 0.f, 0.f, 0.f};                                      \
      _Pragma("unroll")                                                            \
      for (int kc = 0; kc < 24; kc += 2) {                                         \
        bf16x8 av0 = *(const bf16x8*)(sH + aoff0 + kc * 32);                       \
        bf16x8 av1 = *(const bf16x8*)(sH + aoff0 + kc * 32 + 32);                  \
        a0 = __builtin_amdgcn_mfma_f32_16x16x32_bf16(av0, bw[kc],     a0, 0, 0, 0);\
        a1 = __builtin_amdgcn_mfma_f32_16x16x32_bf16(av1, bw[kc + 1], a1, 0, 0, 0);\
      }                                                                            \
      _Pragma("unroll")                                                            \
      for (int r = 0; r < 4; r++)                                                  \
        sG[g * 272 + mrow * 17 + fq * 4 + r] = a0[r] + a1[r];                      \
    }                                                                              \
    wg_barrier_lds();                                                              \
    if (t < 256) {                                                                 \
      float gv0 = sG[0 * 272 + jje * 17 + b16e] + xv0 + ((D) ? bsb0 : bsf0);       \
      float gv1 = sG[1 * 272 + jje * 17 + b16e] + xv1 + ((D) ? bsb1 : bsf1);       \
      float gv2 = sG[2 * 272 + jje * 17 + b16e] + xv2 + ((D) ? bsb2 : bsf2);       \
      float gv3 = sG[3 * 272 + jje * 17 + b16e] + xv3 + ((D) ? bsb3 : bsf3);       \
      gv0 = 1.f / (1.f + __expf(-gv0));                                            \
      gv1 = 1.f / (1.f + __expf(-gv1));                                            \
      gv2 = 1.f - 2.f / (__expf(2.f * gv2) + 1.f);                                 \
      gv3 = 1.f / (1.f + __expf(-gv3));                                            \
      CST = gv1 * CST + gv0 * gv2;                                                 \
      float hv = gv3 * (1.f - 2.f / (__expf(2.f * CST) + 1.f));                    \
      union { bf16_t b; unsigned short u; } pk;                                    \
      pk.b = (bf16_t)hv;                                                           \
      unsigned tag = (unsigned)(tagbase + s);                                      \
      long ed = ((long)((s & 1) * 2 + (D)) * 32 + (BGc) * 16 + b16e) * 768 + j0 + jje; \
      __hip_atomic_store(E + ed, (tag << 16) | pk.u,                               \
                         __ATOMIC_RELAXED, __HIP_MEMORY_SCOPE_AGENT);              \
      mout[((long)((BGc) * 16 + b16e) * TT + tc) * 1536 + (D) * 768 + j0 + jje] = pk.b; \
    }                                                                              \
  }

__global__ __launch_bounds__(512) void k_lstm(
    const bf16_t* __restrict__ xg, bf16_t* __restrict__ mout,
    unsigned* __restrict__ E,
    const float* __restrict__ whh_f, const float* __restrict__ whh_b,
    const float* __restrict__ bias_f, const float* __restrict__ bias_b,
    int tagbase)
{
  __shared__ bf16_t sH[16 * 776];   // 24,832 B
  __shared__ float  sG[4 * 272];    //  4,352 B => 29,184 B total
  const int t    = threadIdx.x;
  const int lane = t & 63;
  const int w    = t >> 6;                 // wave 0..7
  const int g    = w & 3;                  // gate
  const int wd   = w >> 2;                 // wave's dir
  const int j0   = blockIdx.x * 16;        // col slice base
  const int mrow = lane & 15;
  const int fq   = lane >> 4;
  const int jje  = t & 15;                 // epilogue col (t<256)
  const int b16e = (t >> 4) & 15;          // epilogue batch (t<256)

  // stage this wave's whh tile into registers (B operand), f32 -> bf16.
  // lane (mrow,fq) holds whh_wd[g*768 + j0 + mrow][kc*32 + fq*8 .. +8]
  const float* whh = wd ? whh_b : whh_f;
  bf16x8 bw[24];
  {
    const float* wrow = whh + (long)(g * 768 + j0 + mrow) * 768 + fq * 8;
    #pragma unroll
    for (int kc = 0; kc < 24; kc++) {
      f32x4 v0 = *(const f32x4*)(wrow + kc * 32);
      f32x4 v1 = *(const f32x4*)(wrow + kc * 32 + 4);
      bf16x8 bb;
      #pragma unroll
      for (int e = 0; e < 4; e++) { bb[e] = (bf16_t)v0[e]; bb[e + 4] = (bf16_t)v1[e]; }
      bw[kc] = bb;
    }
  }

  // biases for both dirs at this thread's epilogue col
  const float bsf0 = bias_f[0 * 768 + j0 + jje];
  const float bsf1 = bias_f[1 * 768 + j0 + jje];
  const float bsf2 = bias_f[2 * 768 + j0 + jje];
  const float bsf3 = bias_f[3 * 768 + j0 + jje];
  const float bsb0 = bias_b[0 * 768 + j0 + jje];
  const float bsb1 = bias_b[1 * 768 + j0 + jje];
  const float bsb2 = bias_b[2 * 768 + j0 + jje];
  const float bsb3 = bias_b[3 * 768 + j0 + jje];

  // loop-invariant consumer offsets: e = i*512+t covers 16 batches x 384 qwords
  int soff[12];
  #pragma unroll
  for (int i = 0; i < 12; i++) {
    int e = i * 512 + t;
    soff[i] = (e / 384) * 1552 + (e % 384) * 4;  // sH byte offset (2 bf16 per qword)
  }

  const int aoff0 = mrow * 776 + fq * 8;

  float cst00 = 0.f, cst01 = 0.f, cst10 = 0.f, cst11 = 0.f;
  ull qvA[12] = {}, qvB[12] = {};

  for (int s = 0; s < TT; s++) {
    // P0: check C0(s-1) [issued at P2(s-1)]; issue C2(s-1) [stored P2(s-1)]
    LSTM_PHASE(0, 0, cst00, qvA, 1, 0, ((s - 1) & 1))
    // P1: check C1(s-1); issue C3(s-1)
    LSTM_PHASE(0, 1, cst01, qvB, 1, 1, ((s - 1) & 1))
    // P2: check C2(s-1); issue C0(s) [stored this iteration at P0]
    LSTM_PHASE(1, 0, cst10, qvA, 0, 0, (s & 1))
    // P3: check C3(s-1); issue C1(s)
    LSTM_PHASE(1, 1, cst11, qvB, 0, 1, (s & 1))
  }
}

// --------------------------- attention helpers -----------------------------

__global__ __launch_bounds__(256) void k_pack(
    const float* __restrict__ c, const float* __restrict__ q,
    const float* __restrict__ wcq, bf16_t* __restrict__ cw, bf16_t* __restrict__ qb)
{
  int i = blockIdx.x * 256 + threadIdx.x;        // 43008 blocks -> 11,010,048
  if (i < 9437184) {
    int h = i % 768;
    cw[i] = (bf16_t)(c[i] * wcq[h]);
  } else {
    int j = i - 9437184;
    qb[j] = (bf16_t)q[j];
  }
}

__global__ __launch_bounds__(256) void k_proj(
    const float* __restrict__ c, const float* __restrict__ q,
    const float* __restrict__ wc, const float* __restrict__ bc,
    const float* __restrict__ wq, const float* __restrict__ bq,
    float* __restrict__ projc, float* __restrict__ projq)
{
  int row  = blockIdx.x * 4 + (threadIdx.x >> 6);  // 0..14335
  int lane = threadIdx.x & 63;
  const float *src, *w;
  bool isC = row < 12288;
  if (isC) { src = c + (long)row * 768;          w = wc; }
  else     { src = q + (long)(row - 12288) * 768; w = wq; }
  float a = 0.f;
  for (int k = lane * 4; k < 768; k += 256) {
    f32x4 v = *(const f32x4*)(src + k);
    f32x4 wv = *(const f32x4*)(w + k);
    a += v[0]*wv[0] + v[1]*wv[1] + v[2]*wv[2] + v[3]*wv[3];
  }
  for (int m = 32; m; m >>= 1) a += __shfl_xor(a, m);
  if (lane == 0) {
    if (isC) projc[row] = a + bc[0];
    else     projq[row - 12288] = a + bq[0];
  }
}

__global__ __launch_bounds__(256) void k_smax_j(
    const float* __restrict__ s, bf16_t* __restrict__ a, float* __restrict__ smax)
{
  int row  = blockIdx.x * 4 + (threadIdx.x >> 6);
  int lane = threadIdx.x & 63;
  float v = s[(long)row * 64 + lane];
  float mx = v;
  for (int m = 32; m; m >>= 1) mx = fmaxf(mx, __shfl_xor(mx, m));
  float p = __expf(v - mx);
  float sum = p;
  for (int m = 32; m; m >>= 1) sum += __shfl_xor(sum, m);
  a[(long)row * 64 + lane] = (bf16_t)(p / sum);
  if (lane == 0) smax[row] = mx;
}

__global__ __launch_bounds__(384) void k_smax_i(
    const float* __restrict__ smax, float* __restrict__ bw)
{
  __shared__ float red[8];
  int b = blockIdx.x, t = threadIdx.x;   // 384 threads, 6 waves
  int lane = t & 63, wv = t >> 6;
  float v = smax[b * 384 + t];
  float mx = v;
  for (int m = 32; m; m >>= 1) mx = fmaxf(mx, __shfl_xor(mx, m));
  if (lane == 0) red[wv] = mx;
  __syncthreads();
  float gm = red[0];
  #pragma unroll
  for (int i = 1; i < 6; i++) gm = fmaxf(gm, red[i]);
  float p = __expf(v - gm);
  float sm = p;
  for (int m = 32; m; m >>= 1) sm += __shfl_xor(sm, m);
  __syncthreads();
  if (lane == 0) red[wv] = sm;
  __syncthreads();
  float tot = red[0];
  #pragma unroll
  for (int i = 1; i < 6; i++) tot += red[i];
  bw[b * 384 + t] = p / tot;
}

__global__ __launch_bounds__(256) void k_q2c(
    const float* __restrict__ bw, const float* __restrict__ c, float* __restrict__ q2c)
{
  int b = blockIdx.y;
  int h = blockIdx.x * 256 + threadIdx.x;
  const float* cb = c + (long)b * 384 * 768;
  float acc = 0.f;
  for (int i = 0; i < 384; i++) acc += bw[b * 384 + i] * cb[(long)i * 768 + h];
  q2c[b * 768 + h] = acc;
}

__global__ __launch_bounds__(256) void k_tq(
    const bf16_t* __restrict__ qb, bf16_t* __restrict__ qT)
{
  __shared__ bf16_t sT[64][72];
  int b = blockIdx.y, hc = blockIdx.x, t = threadIdx.x;
  {
    int j = t >> 2, h0 = (t & 3) * 16;
    const bf16_t* src = qb + (long)(b * 64 + j) * 768 + hc * 64 + h0;
    *(bf16x8*)&sT[j][h0]     = *(const bf16x8*)(src);
    *(bf16x8*)&sT[j][h0 + 8] = *(const bf16x8*)(src + 8);
  }
  __syncthreads();
  {
    int h = t >> 2, j0 = (t & 3) * 16;
    bf16x8 o0, o1;
    #pragma unroll
    for (int e = 0; e < 8; e++) { o0[e] = sT[j0 + e][h]; o1[e] = sT[j0 + 8 + e][h]; }
    bf16_t* dst = qT + (long)(b * 768 + hc * 64 + h) * 64 + j0;
    *(bf16x8*)dst       = o0;
    *(bf16x8*)(dst + 8) = o1;
  }
}

__global__ __launch_bounds__(256) void k_buildg(
    const float* __restrict__ c, const bf16_t* __restrict__ c2q,
    const float* __restrict__ q2c, bf16_t* __restrict__ g)
{
  int i = blockIdx.x * 256 + threadIdx.x;   // < 9,437,184
  int h = i % 768;
  int row = i / 768;
  int b = row / 384;
  float cv  = c[i];
  float cqv = (float)c2q[i];
  float qcv = q2c[b * 768 + h];
  bf16_t* gr = g + (long)row * 3072;
  gr[h]        = (bf16_t)cv;
  gr[768 + h]  = c2q[i];
  gr[1536 + h] = (bf16_t)(cv * cqv);
  gr[2304 + h] = (bf16_t)(cv * qcv);
}

// heads: g-part (both p1 and p2), one pass over g
__global__ __launch_bounds__(256) void k_headsg(
    const bf16_t* __restrict__ g, const float* __restrict__ w1, const float* __restrict__ w2,
    float* __restrict__ pg1, float* __restrict__ pg2)
{
  int row  = blockIdx.x * 4 + (threadIdx.x >> 6);  // 0..12287
  int lane = threadIdx.x & 63;
  float a1 = 0.f, a2 = 0.f;
  const bf16_t* gr = g + (long)row * 3072;
  for (int k = lane * 8; k < 3072; k += 512) {
    bf16x8 v = *(const bf16x8*)(gr + k);
    f32x4 wa = *(const f32x4*)(w1 + k), wb = *(const f32x4*)(w1 + k + 4);
    f32x4 xa = *(const f32x4*)(w2 + k), xb = *(const f32x4*)(w2 + k + 4);
    #pragma unroll
    for (int e = 0; e < 4; e++) {
      a1 += (float)v[e] * wa[e] + (float)v[e + 4] * wb[e];
      a2 += (float)v[e] * xa[e] + (float)v[e + 4] * xb[e];
    }
  }
  for (int m_ = 32; m_; m_ >>= 1) { a1 += __shfl_xor(a1, m_); a2 += __shfl_xor(a2, m_); }
  if (lane == 0) { pg1[row] = a1; pg2[row] = a2; }
}

// heads: m-part, writes final output rows
__global__ __launch_bounds__(256) void k_headsm(
    const bf16_t* __restrict__ m, const float* __restrict__ wm,
    const float* __restrict__ pg, const float* __restrict__ bg,
    const float* __restrict__ bm, float* __restrict__ out)
{
  int row  = blockIdx.x * 4 + (threadIdx.x >> 6);  // 0..12287
  int lane = threadIdx.x & 63;
  float a = 0.f;
  const bf16_t* mr = m + (long)row * 1536;
  for (int k = lane * 8; k < 1536; k += 512) {
    bf16x8 v = *(const bf16x8*)(mr + k);
    f32x4 wa = *(const f32x4*)(wm + k), wb = *(const f32x4*)(wm + k + 4);
    #pragma unroll
    for (int e = 0; e < 4; e++) a += (float)v[e] * wa[e] + (float)v[e + 4] * wb[e];
  }
  for (int m_ = 32; m_; m_ >>= 1) a += __shfl_xor(a, m_);
  if (lane == 0) out[row] = pg[row] + a + bg[0] + bm[0];
}

// ---------------------------------------------------------------------------

extern "C" void kernel_launch(void* const* d_in, const int* in_sizes, int n_in,
                              void* d_out, int out_size, void* d_ws, size_t ws_size,
                              hipStream_t stream)
{
  (void)in_sizes; (void)n_in; (void)out_size; (void)ws_size;
  const float* c    = (const float*)d_in[0];
  const float* q    = (const float*)d_in[1];
  const float* wac  = (const float*)d_in[2];
  const float* bac  = (const float*)d_in[3];
  const float* waq  = (const float*)d_in[4];
  const float* baq  = (const float*)d_in[5];
  const float* wacq = (const float*)d_in[6];
  const float* bacq = (const float*)d_in[7];
  const float* l1f_wih = (const float*)d_in[8];
  const float* l1f_whh = (const float*)d_in[9];
  const float* l1f_b   = (const float*)d_in[10];
  const float* l1b_wih = (const float*)d_in[11];
  const float* l1b_whh = (const float*)d_in[12];
  const float* l1b_b   = (const float*)d_in[13];
  const float* l2f_wih = (const float*)d_in[14];
  const float* l2f_whh = (const float*)d_in[15];
  const float* l2f_b   = (const float*)d_in[16];
  const float* l2b_wih = (const float*)d_in[17];
  const float* l2b_whh = (const float*)d_in[18];
  const float* l2b_b   = (const float*)d_in[19];
  const float* lof_wih = (const float*)d_in[20];
  const float* lof_whh = (const float*)d_in[21];
  const float* lof_b   = (const float*)d_in[22];
  const float* lob_wih = (const float*)d_in[23];
  const float* lob_whh = (const float*)d_in[24];
  const float* lob_b   = (const float*)d_in[25];
  const float* p1wg = (const float*)d_in[26];
  const float* p1bg = (const float*)d_in[27];
  const float* p1wm = (const float*)d_in[28];
  const float* p1bm = (const float*)d_in[29];
  const float* p2wg = (const float*)d_in[30];
  const float* p2bg = (const float*)d_in[31];
  const float* p2wm = (const float*)d_in[32];
  const float* p2bm = (const float*)d_in[33];

  // workspace layout (total ~227.6 MB)
  char* ws = (char*)d_ws;
  bf16_t* g_bf = (bf16_t*)ws;                       // [0, 75.5MB) g
  bf16_t* mA   = (bf16_t*)ws;                       // aliases g (g dead by stage1 lstm)
  bf16_t* mB   = (bf16_t*)(ws + 37748736L);         // second half of g region
  bf16_t* m2   = (bf16_t*)ws;                       // aliases mA (dead after stage2 GEMM)
  char*   xgc  = ws + 75497472L;                    // [75.5MB, 226.5MB) xg
  bf16_t* xg   = (bf16_t*)xgc;
  // attention temps alias the xg region (dead before stage1 GEMM writes xg)
  bf16_t* cw  = (bf16_t*)xgc;                       // 18,874,368
  bf16_t* qb  = (bf16_t*)(xgc + 18874368L);         //  3,145,728
  bf16_t* qT  = (bf16_t*)(xgc + 22020096L);         //  3,145,728
  float*  sS  = (float*) (xgc + 25165824L);         //  3,145,728
  bf16_t* aP  = (bf16_t*)(xgc + 28311552L);         //  1,572,864
  bf16_t* c2q = (bf16_t*)(xgc + 29884416L);         // 18,874,368
  char* tail = ws + 226492416L;
  float*    projc = (float*)tail;                   // 49,152
  float*    projq = (float*)(tail + 49152);         //  8,192
  float*    smax  = (float*)(tail + 57344);         // 49,152
  float*    bw    = (float*)(tail + 106496);        // 49,152
  float*    q2c   = (float*)(tail + 155648);        // 98,304
  float*    pg1   = (float*)(tail + 253952);        // 49,152
  float*    pg2   = (float*)(tail + 303104);        // 49,152
  unsigned* E     = (unsigned*)(tail + 352256);     // 2par x 2dir x 32 x 768 x 4B = 786,432

  k_zeroE<<<768, 256, 0, stream>>>(E);

  // ---- attention ----
  k_pack<<<43008, 256, 0, stream>>>(c, q, wacq, cw, qb);
  k_proj<<<3584, 256, 0, stream>>>(c, q, wac, bac, waq, baq, projc, projq);
  k_gemm<64,1,0><<<dim3(3,1,32), 256, 0, stream>>>(cw, qb, nullptr, 1<<30, sS,
      384, 64, 768, (long)384*768, (long)64*768, (long)384*64, projc, projq, bacq);
  k_smax_j<<<3072, 256, 0, stream>>>(sS, aP, smax);
  k_smax_i<<<32, 384, 0, stream>>>(smax, bw);
  k_q2c<<<dim3(3,32), 256, 0, stream>>>(bw, c, q2c);
  k_tq<<<dim3(12,32), 256, 0, stream>>>(qb, qT);
  k_gemm<64,0,0><<<dim3(3,12,32), 256, 0, stream>>>(aP, qT, nullptr, 1<<30, c2q,
      384, 768, 64, (long)384*64, (long)768*64, (long)384*768, nullptr, nullptr, nullptr);
  k_buildg<<<36864, 256, 0, stream>>>(c, c2q, q2c, g_bf);
  k_headsg<<<3072, 256, 0, stream>>>(g_bf, p1wg, p2wg, pg1, pg2);

  // ---- stage 1 (input 4H=3072) ----
  k_gemm<128,0,1><<<dim3(96,48,1), 256, 0, stream>>>(g_bf, l1f_wih, l1b_wih, 3072, xg,
      12288, 6144, 3072, 0, 0, 0, nullptr, nullptr, nullptr);
  k_lstm<<<48, 512, 0, stream>>>(xg, mA, E, l1f_whh, l1b_whh, l1f_b, l1b_b, 0);

  // ---- stage 2 (input 2H=1536) ----
  k_gemm<128,0,1><<<dim3(96,48,1), 256, 0, stream>>>(mA, l2f_wih, l2b_wih, 3072, xg,
      12288, 6144, 1536, 0, 0, 0, nullptr, nullptr, nullptr);
  k_lstm<<<48, 512, 0, stream>>>(xg, mB, E, l2f_whh, l2b_whh, l2f_b, l2b_b, 384);
  k_headsm<<<3072, 256, 0, stream>>>(mB, p1wm, pg1, p1bg, p1bm, (float*)d_out);

  // ---- stage 3 (output LSTM, input 2H=1536) ----
  k_gemm<128,0,1><<<dim3(96,48,1), 256, 0, stream>>>(mB, lof_wih, lob_wih, 3072, xg,
      12288, 6144, 1536, 0, 0, 0, nullptr, nullptr, nullptr);
  k_lstm<<<48, 512, 0, stream>>>(xg, m2, E, lof_whh, lob_whh, lof_b, lob_b, 768);
  k_headsm<<<3072, 256, 0, stream>>>(m2, p2wm, pg2, p2bg, p2bm, (float*)d_out + 12288);
}

// Round 3
// 10507.728 us; speedup vs baseline: 1.0149x; 1.0149x over previous
//
#include <hip/hip_runtime.h>

// ---------------------------------------------------------------------------
// BiDAF block: B=32, CLEN=384, QLEN=64, H=768
// Workspace layout (~228MB):
//   [0, 75.5MB)    g  (later: mA @0, mB @37.7MB, m2 @0)
//   [75.5, 226.5)  xg (attention temps alias the front of this region)
//   [226.5, +)     tail scalars + E exchange buffer (786KB)
// R5: k_lstm exchange = tag-in-data dwords {tag:16|bf16 h:16} in LLC-resident
// E buffer, parity double-buffered. Consumers poll data tags directly: one
// rendezvous per step (R7's 4-phase interleave REGRESSED: rendezvous cost is
// max-skew over participants, paid per rendezvous — don't multiply them).
// R8: 64-col slices (grid 48 = dir x 12 slices x bg2, 1024 thr = 16 waves,
// wave = gate x col-quarter, whh 96 VGPR/lane) -> 12 rendezvous participants
// per chain (was 24). Producer lane-pairs pack h into single 64-bit E stores
// (no half-stale qwords). xg gate values prefetched one step ahead; in-loop
// barriers are lgkm-only so prefetch loads stay in flight across steps.
// ---------------------------------------------------------------------------

typedef __bf16 bf16_t;
typedef __bf16 bf16x4 __attribute__((ext_vector_type(4)));
typedef __bf16 bf16x8 __attribute__((ext_vector_type(8)));
typedef float  f32x4  __attribute__((ext_vector_type(4)));
typedef unsigned long long ull;

#define TT 384

__device__ __forceinline__ void gload_lds16(const void* g, void* l) {
  __builtin_amdgcn_global_load_lds((const __attribute__((address_space(1))) void*)g,
                                   (__attribute__((address_space(3))) void*)l, 16, 0, 0);
}

// workgroup barrier ordering LDS only: does NOT drain vmcnt, so global loads
// issued earlier (xg prefetch, polls) stay in flight across it.
__device__ __forceinline__ void wg_barrier_lds() {
  asm volatile("s_waitcnt lgkmcnt(0)" ::: "memory");
  __builtin_amdgcn_s_barrier();
  asm volatile("" ::: "memory");
}

// set all E tags to 0xFFFF (never matches a wanted tag in [0,1152))
__global__ void k_zeroE(unsigned* p) {
  int i = blockIdx.x * 256 + threadIdx.x;
  __hip_atomic_store(p + i, 0xFFFF0000u, __ATOMIC_RELAXED, __HIP_MEMORY_SCOPE_AGENT);
}

// ---------------------------------------------------------------------------
// GEMM: C[M,N] = A[M,K] * B[N,K]^T, A bf16 K-contig (global_load_lds).
// BSRC=0: B bf16 via global_load_lds (Bv + bz*sBb). BSRC=1: B fp32 from
// Bv (rows < nsplit) / Bv2 (rows >= nsplit), converted during staging.
// BM=128, BK=32, 256 threads = 4 waves (2x2), wave tile 64 x (BN/2).
// EPI=0: bf16 out. EPI=1: f32 out + rowb[bz*M+row] + colb[bz*N+col] + *sb.
// ---------------------------------------------------------------------------
template<int BN, int EPI, int BSRC>
__global__ __launch_bounds__(256) void k_gemm(
    const bf16_t* __restrict__ A, const void* __restrict__ Bv, const void* __restrict__ Bv2,
    int nsplit, void* __restrict__ Cv,
    int M, int N, int K, long sAb, long sBb, long sCb,
    const float* __restrict__ rowb, const float* __restrict__ colb,
    const float* __restrict__ sb)
{
  constexpr int BM = 128, BK = 32;
  constexpr int NT = BN / 32;          // 16-wide N tiles per wave
  __shared__ bf16_t sA[BM * BK];
  __shared__ bf16_t sB[BN * BK];
  const int t    = threadIdx.x;
  const int lane = t & 63;
  const int wm   = (t >> 6) >> 1, wn = (t >> 6) & 1;
  const long bz  = blockIdx.z;
  const int nbase = blockIdx.y * BN;
  const bf16_t* Ab = A + bz * sAb + (long)blockIdx.x * BM * K;
  const bf16_t* Bb = nullptr;
  const float*  Bf = nullptr;
  if constexpr (BSRC == 0)
    Bb = (const bf16_t*)Bv + bz * sBb + (long)nbase * K;
  else
    Bf = (nbase < nsplit) ? ((const float*)Bv  + (long)nbase * K)
                          : ((const float*)Bv2 + (long)(nbase - nsplit) * K);

  const int r4 = t >> 2;                          // staging row 0..63
  const int kq = (t & 3) ^ ((r4 >> 1) & 3);       // XOR-swizzled source k-quad

  f32x4 acc[4][NT];
  #pragma unroll
  for (int i = 0; i < 4; i++)
    #pragma unroll
    for (int j = 0; j < NT; j++) acc[i][j] = (f32x4){0.f, 0.f, 0.f, 0.f};

  const int mrow = lane & 15;
  const int fq   = lane >> 4;
  const int aswz = (fq ^ ((mrow >> 1) & 3)) * 8;  // swizzled frag k-offset (elems)

  for (int k0 = 0; k0 < K; k0 += BK) {
    __syncthreads();
    gload_lds16(Ab + (long)r4 * K + k0 + kq * 8,        (char*)sA + t * 16);
    gload_lds16(Ab + (long)(64 + r4) * K + k0 + kq * 8, (char*)sA + 4096 + t * 16);
    if constexpr (BSRC == 0) {
      gload_lds16(Bb + (long)r4 * K + k0 + kq * 8,        (char*)sB + t * 16);
      if constexpr (BN == 128)
        gload_lds16(Bb + (long)(64 + r4) * K + k0 + kq * 8, (char*)sB + 4096 + t * 16);
    } else {
      {
        f32x4 b0 = *(const f32x4*)(Bf + (long)r4 * K + k0 + kq * 8);
        f32x4 b1 = *(const f32x4*)(Bf + (long)r4 * K + k0 + kq * 8 + 4);
        bf16x8 bb;
        #pragma unroll
        for (int e = 0; e < 4; e++) { bb[e] = (bf16_t)b0[e]; bb[e + 4] = (bf16_t)b1[e]; }
        *(bf16x8*)((char*)sB + t * 16) = bb;
      }
      if constexpr (BN == 128) {
        f32x4 b0 = *(const f32x4*)(Bf + (long)(64 + r4) * K + k0 + kq * 8);
        f32x4 b1 = *(const f32x4*)(Bf + (long)(64 + r4) * K + k0 + kq * 8 + 4);
        bf16x8 bb;
        #pragma unroll
        for (int e = 0; e < 4; e++) { bb[e] = (bf16_t)b0[e]; bb[e + 4] = (bf16_t)b1[e]; }
        *(bf16x8*)((char*)sB + 4096 + t * 16) = bb;
      }
    }
    __syncthreads();

    bf16x8 af[4], bv[NT];
    #pragma unroll
    for (int mt = 0; mt < 4; mt++)
      af[mt] = *(const bf16x8*)(sA + (wm * 64 + mt * 16 + mrow) * 32 + aswz);
    #pragma unroll
    for (int nt = 0; nt < NT; nt++)
      bv[nt] = *(const bf16x8*)(sB + (wn * (BN / 2) + nt * 16 + mrow) * 32 + aswz);
    #pragma unroll
    for (int mt = 0; mt < 4; mt++)
      #pragma unroll
      for (int nt = 0; nt < NT; nt++)
        acc[mt][nt] = __builtin_amdgcn_mfma_f32_16x16x32_bf16(af[mt], bv[nt], acc[mt][nt], 0, 0, 0);
  }

  const int rbase = (lane >> 4) * 4;
  #pragma unroll
  for (int mt = 0; mt < 4; mt++)
    #pragma unroll
    for (int nt = 0; nt < NT; nt++)
      #pragma unroll
      for (int r = 0; r < 4; r++) {
        int grow = blockIdx.x * BM + wm * 64 + mt * 16 + rbase + r;
        int gcol = nbase + wn * (BN / 2) + nt * 16 + (lane & 15);
        if constexpr (EPI == 0) {
          ((bf16_t*)Cv)[bz * sCb + (long)grow * N + gcol] = (bf16_t)acc[mt][nt][r];
        } else {
          ((float*)Cv)[bz * sCb + (long)grow * N + gcol] =
              acc[mt][nt][r] + rowb[bz * M + grow] + colb[bz * N + gcol] + sb[0];
        }
      }
}

// ---------------------------------------------------------------------------
// Recurrent biLSTM stage. grid = 48: dir(2) x slice(12) x bg(2), 1024 threads
// = 16 waves. Block owns 64 h-cols x 16 batches. Wave w: gate g = w&3,
// col-quarter ch = w>>2; its 16-col whh tile lives in VGPRs (24 x bf16x8 =
// 96 VGPR/lane). LDS: sH (h staging, 776-elem padded rows) + sG (gate
// exchange, stride-17 padded). Exchange: E qwords of paired dwords
// {tag:16|bf16 h:16}, parity double-buffered, relaxed AGENT atomics.
// Producer lane-pairs pack two cols into ONE 64-bit store (qword tag halves
// can never be observed split). Consumers poll tags directly — one
// rendezvous per step over 12 producer blocks.
// xg: [B*T, 6144] bf16 (fwd 4H | bwd 4H, gate order i,f,g,o); values for
// step s+1 are prefetched during step s (xn -> xc rotate); in-loop barriers
// are lgkm-only so those loads stay in flight.
// mout: [B, T, 2H] bf16 (fwd | bwd) — plain paired stores.
// ---------------------------------------------------------------------------
__global__ __launch_bounds__(1024) void k_lstm(
    const bf16_t* __restrict__ xg, bf16_t* __restrict__ mout,
    unsigned* __restrict__ E,
    const float* __restrict__ whh_f, const float* __restrict__ whh_b,
    const float* __restrict__ bias_f, const float* __restrict__ bias_b,
    int tagbase)
{
  __shared__ bf16_t sH[16 * 776];      // 24,832 B
  __shared__ float  sG[4 * 64 * 17];   // 17,408 B => 42,240 B total
  const int t    = threadIdx.x;
  const int lane = t & 63;
  const int w    = t >> 6;                 // wave 0..15
  const int g    = w & 3;                  // gate
  const int ch   = w >> 2;                 // col quarter 0..3
  const int blk  = blockIdx.x;
  const int dir  = blk / 24;
  const int qq   = blk - dir * 24;
  const int sl   = qq >> 1;                // slice 0..11
  const int bg   = qq & 1;                 // batch group 0..1
  const int j0   = sl * 64;
  const float* whh  = dir ? whh_b : whh_f;
  const float* bias = dir ? bias_b : bias_f;

  const int mrow = lane & 15;
  const int fq   = lane >> 4;

  // stage this wave's whh tile into registers (B operand), f32 -> bf16.
  // lane (mrow,fq) holds whh[g*768 + j0 + ch*16 + mrow][kc*32 + fq*8 .. +8]
  bf16x8 bw[24];
  {
    const float* wrow = whh + (long)(g * 768 + j0 + ch * 16 + mrow) * 768 + fq * 8;
    #pragma unroll
    for (int kc = 0; kc < 24; kc++) {
      f32x4 v0 = *(const f32x4*)(wrow + kc * 32);
      f32x4 v1 = *(const f32x4*)(wrow + kc * 32 + 4);
      bf16x8 bb;
      #pragma unroll
      for (int e = 0; e < 4; e++) { bb[e] = (bf16_t)v0[e]; bb[e + 4] = (bf16_t)v1[e]; }
      bw[kc] = bb;
    }
  }

  const int jje  = t & 63;                 // epilogue col 0..63
  const int b16e = t >> 6;                 // epilogue batch 0..15 (== wave)
  float bsv[4];
  #pragma unroll
  for (int gi = 0; gi < 4; gi++) bsv[gi] = bias[gi * 768 + j0 + jje];

  // loop-invariant consumer offsets: e = i*1024+t covers 16 batches x 384 qwords
  int soff[6];
  #pragma unroll
  for (int i = 0; i < 6; i++) {
    int e = i * 1024 + t;
    soff[i] = (e / 384) * 1552 + (e % 384) * 4;  // sH byte offset (2 bf16 per qword)
  }

  float cst = 0.f;
  const int aoff0 = mrow * 776 + fq * 8;
  const long xrow0 = (long)(bg * 16 + b16e) * TT;

  // prefetch xg gate values for step 0
  float xc[4], xn[4];
  {
    int tc0 = dir ? (TT - 1) : 0;
    long xr = (xrow0 + tc0) * 6144 + dir * 3072 + j0 + jje;
    #pragma unroll
    for (int gi = 0; gi < 4; gi++) xn[gi] = (float)xg[xr + gi * 768];
  }

  for (int s = 0; s < TT; s++) {
    const int tc = dir ? (TT - 1 - s) : s;

    // rotate prefetch: xc = this step's gate values; issue next step's loads
    #pragma unroll
    for (int gi = 0; gi < 4; gi++) xc[gi] = xn[gi];
    {
      int sn = (s + 1 < TT) ? s + 1 : s;
      int tcn = dir ? (TT - 1 - sn) : sn;
      long xr = (xrow0 + tcn) * 6144 + dir * 3072 + j0 + jje;
      #pragma unroll
      for (int gi = 0; gi < 4; gi++) xn[gi] = (float)xg[xr + gi * 768];
    }

    if (s == 0) {
      for (int e = t; e < 1552; e += 1024)
        *(f32x4*)((char*)sH + e * 16) = (f32x4){0.f, 0.f, 0.f, 0.f};
    } else {
      const unsigned want = (unsigned)(tagbase + s - 1);
      const int par = (s - 1) & 1;
      const ull* src = (const ull*)E + ((long)(par * 2 + dir) * 32 + bg * 16) * 384;
      ull qv[6];
      #pragma unroll
      for (int i = 0; i < 6; i++)
        qv[i] = __hip_atomic_load(src + i * 1024 + t, __ATOMIC_RELAXED, __HIP_MEMORY_SCOPE_AGENT);
      for (;;) {
        unsigned bad = 0;
        #pragma unroll
        for (int i = 0; i < 6; i++) {
          unsigned lo = (unsigned)qv[i], hi = (unsigned)(qv[i] >> 32);
          if ((lo >> 16) != want || (hi >> 16) != want) bad |= 1u << i;
        }
        if (!bad) break;
        #pragma unroll
        for (int i = 0; i < 6; i++)
          if (bad & (1u << i))
            qv[i] = __hip_atomic_load(src + i * 1024 + t, __ATOMIC_RELAXED, __HIP_MEMORY_SCOPE_AGENT);
      }
      #pragma unroll
      for (int i = 0; i < 6; i++) {
        ushort2 hh;
        hh.x = (unsigned short)qv[i];
        hh.y = (unsigned short)(qv[i] >> 32);
        *(ushort2*)((char*)sH + soff[i]) = hh;
      }
    }
    wg_barrier_lds();

    // two independent 12-deep accumulate chains over K=768
    f32x4 a0 = (f32x4){0.f, 0.f, 0.f, 0.f};
    f32x4 a1 = (f32x4){0.f, 0.f, 0.f, 0.f};
    #pragma unroll
    for (int kc = 0; kc < 24; kc += 2) {
      bf16x8 av0 = *(const bf16x8*)(sH + aoff0 + kc * 32);
      bf16x8 av1 = *(const bf16x8*)(sH + aoff0 + kc * 32 + 32);
      a0 = __builtin_amdgcn_mfma_f32_16x16x32_bf16(av0, bw[kc],     a0, 0, 0, 0);
      a1 = __builtin_amdgcn_mfma_f32_16x16x32_bf16(av1, bw[kc + 1], a1, 0, 0, 0);
    }
    #pragma unroll
    for (int r = 0; r < 4; r++)
      sG[g * 1088 + (ch * 16 + mrow) * 17 + fq * 4 + r] = a0[r] + a1[r];
    wg_barrier_lds();

    {
      float gv0 = sG[0 * 1088 + jje * 17 + b16e] + xc[0] + bsv[0];
      float gv1 = sG[1 * 1088 + jje * 17 + b16e] + xc[1] + bsv[1];
      float gv2 = sG[2 * 1088 + jje * 17 + b16e] + xc[2] + bsv[2];
      float gv3 = sG[3 * 1088 + jje * 17 + b16e] + xc[3] + bsv[3];
      gv0 = 1.f / (1.f + __expf(-gv0));
      gv1 = 1.f / (1.f + __expf(-gv1));
      gv2 = 1.f - 2.f / (__expf(2.f * gv2) + 1.f);
      gv3 = 1.f / (1.f + __expf(-gv3));
      cst = gv1 * cst + gv0 * gv2;
      float hv = gv3 * (1.f - 2.f / (__expf(2.f * cst) + 1.f));
      union { bf16_t b; unsigned short u; } pk;
      pk.b = (bf16_t)hv;
      unsigned tag = (unsigned)(tagbase + s);
      unsigned myd = (tag << 16) | pk.u;
      unsigned od  = (unsigned)__shfl_xor((int)myd, 1);   // partner col's dword
      if ((t & 1) == 0) {
        long ed = ((long)((s & 1) * 2 + dir) * 32 + bg * 16 + b16e) * 768 + j0 + jje;
        __hip_atomic_store((ull*)E + (ed >> 1), (ull)myd | ((ull)od << 32),
                           __ATOMIC_RELAXED, __HIP_MEMORY_SCOPE_AGENT);
        unsigned mo = (unsigned)pk.u | ((od & 0xFFFFu) << 16);
        *(unsigned*)(mout + (xrow0 + tc) * 1536 + dir * 768 + j0 + jje) = mo;
      }
    }
    // no end-of-step barrier: next iteration's sH overwrite is fenced by the
    // post-fill barrier (all threads passed MFMA+sG reads by then)
  }
}

// --------------------------- attention helpers -----------------------------

__global__ __launch_bounds__(256) void k_pack(
    const float* __restrict__ c, const float* __restrict__ q,
    const float* __restrict__ wcq, bf16_t* __restrict__ cw, bf16_t* __restrict__ qb)
{
  int i = blockIdx.x * 256 + threadIdx.x;        // 43008 blocks -> 11,010,048
  if (i < 9437184) {
    int h = i % 768;
    cw[i] = (bf16_t)(c[i] * wcq[h]);
  } else {
    int j = i - 9437184;
    qb[j] = (bf16_t)q[j];
  }
}

__global__ __launch_bounds__(256) void k_proj(
    const float* __restrict__ c, const float* __restrict__ q,
    const float* __restrict__ wc, const float* __restrict__ bc,
    const float* __restrict__ wq, const float* __restrict__ bq,
    float* __restrict__ projc, float* __restrict__ projq)
{
  int row  = blockIdx.x * 4 + (threadIdx.x >> 6);  // 0..14335
  int lane = threadIdx.x & 63;
  const float *src, *w;
  bool isC = row < 12288;
  if (isC) { src = c + (long)row * 768;          w = wc; }
  else     { src = q + (long)(row - 12288) * 768; w = wq; }
  float a = 0.f;
  for (int k = lane * 4; k < 768; k += 256) {
    f32x4 v = *(const f32x4*)(src + k);
    f32x4 wv = *(const f32x4*)(w + k);
    a += v[0]*wv[0] + v[1]*wv[1] + v[2]*wv[2] + v[3]*wv[3];
  }
  for (int m = 32; m; m >>= 1) a += __shfl_xor(a, m);
  if (lane == 0) {
    if (isC) projc[row] = a + bc[0];
    else     projq[row - 12288] = a + bq[0];
  }
}

__global__ __launch_bounds__(256) void k_smax_j(
    const float* __restrict__ s, bf16_t* __restrict__ a, float* __restrict__ smax)
{
  int row  = blockIdx.x * 4 + (threadIdx.x >> 6);
  int lane = threadIdx.x & 63;
  float v = s[(long)row * 64 + lane];
  float mx = v;
  for (int m = 32; m; m >>= 1) mx = fmaxf(mx, __shfl_xor(mx, m));
  float p = __expf(v - mx);
  float sum = p;
  for (int m = 32; m; m >>= 1) sum += __shfl_xor(sum, m);
  a[(long)row * 64 + lane] = (bf16_t)(p / sum);
  if (lane == 0) smax[row] = mx;
}

__global__ __launch_bounds__(384) void k_smax_i(
    const float* __restrict__ smax, float* __restrict__ bw)
{
  __shared__ float red[8];
  int b = blockIdx.x, t = threadIdx.x;   // 384 threads, 6 waves
  int lane = t & 63, wv = t >> 6;
  float v = smax[b * 384 + t];
  float mx = v;
  for (int m = 32; m; m >>= 1) mx = fmaxf(mx, __shfl_xor(mx, m));
  if (lane == 0) red[wv] = mx;
  __syncthreads();
  float gm = red[0];
  #pragma unroll
  for (int i = 1; i < 6; i++) gm = fmaxf(gm, red[i]);
  float p = __expf(v - gm);
  float sm = p;
  for (int m = 32; m; m >>= 1) sm += __shfl_xor(sm, m);
  __syncthreads();
  if (lane == 0) red[wv] = sm;
  __syncthreads();
  float tot = red[0];
  #pragma unroll
  for (int i = 1; i < 6; i++) tot += red[i];
  bw[b * 384 + t] = p / tot;
}

__global__ __launch_bounds__(256) void k_q2c(
    const float* __restrict__ bw, const float* __restrict__ c, float* __restrict__ q2c)
{
  int b = blockIdx.y;
  int h = blockIdx.x * 256 + threadIdx.x;
  const float* cb = c + (long)b * 384 * 768;
  float acc = 0.f;
  for (int i = 0; i < 384; i++) acc += bw[b * 384 + i] * cb[(long)i * 768 + h];
  q2c[b * 768 + h] = acc;
}

__global__ __launch_bounds__(256) void k_tq(
    const bf16_t* __restrict__ qb, bf16_t* __restrict__ qT)
{
  __shared__ bf16_t sT[64][72];
  int b = blockIdx.y, hc = blockIdx.x, t = threadIdx.x;
  {
    int j = t >> 2, h0 = (t & 3) * 16;
    const bf16_t* src = qb + (long)(b * 64 + j) * 768 + hc * 64 + h0;
    *(bf16x8*)&sT[j][h0]     = *(const bf16x8*)(src);
    *(bf16x8*)&sT[j][h0 + 8] = *(const bf16x8*)(src + 8);
  }
  __syncthreads();
  {
    int h = t >> 2, j0 = (t & 3) * 16;
    bf16x8 o0, o1;
    #pragma unroll
    for (int e = 0; e < 8; e++) { o0[e] = sT[j0 + e][h]; o1[e] = sT[j0 + 8 + e][h]; }
    bf16_t* dst = qT + (long)(b * 768 + hc * 64 + h) * 64 + j0;
    *(bf16x8*)dst       = o0;
    *(bf16x8*)(dst + 8) = o1;
  }
}

__global__ __launch_bounds__(256) void k_buildg(
    const float* __restrict__ c, const bf16_t* __restrict__ c2q,
    const float* __restrict__ q2c, bf16_t* __restrict__ g)
{
  int i = blockIdx.x * 256 + threadIdx.x;   // < 9,437,184
  int h = i % 768;
  int row = i / 768;
  int b = row / 384;
  float cv  = c[i];
  float cqv = (float)c2q[i];
  float qcv = q2c[b * 768 + h];
  bf16_t* gr = g + (long)row * 3072;
  gr[h]        = (bf16_t)cv;
  gr[768 + h]  = c2q[i];
  gr[1536 + h] = (bf16_t)(cv * cqv);
  gr[2304 + h] = (bf16_t)(cv * qcv);
}

// heads: g-part (both p1 and p2), one pass over g
__global__ __launch_bounds__(256) void k_headsg(
    const bf16_t* __restrict__ g, const float* __restrict__ w1, const float* __restrict__ w2,
    float* __restrict__ pg1, float* __restrict__ pg2)
{
  int row  = blockIdx.x * 4 + (threadIdx.x >> 6);  // 0..12287
  int lane = threadIdx.x & 63;
  float a1 = 0.f, a2 = 0.f;
  const bf16_t* gr = g + (long)row * 3072;
  for (int k = lane * 8; k < 3072; k += 512) {
    bf16x8 v = *(const bf16x8*)(gr + k);
    f32x4 wa = *(const f32x4*)(w1 + k), wb = *(const f32x4*)(w1 + k + 4);
    f32x4 xa = *(const f32x4*)(w2 + k), xb = *(const f32x4*)(w2 + k + 4);
    #pragma unroll
    for (int e = 0; e < 4; e++) {
      a1 += (float)v[e] * wa[e] + (float)v[e + 4] * wb[e];
      a2 += (float)v[e] * xa[e] + (float)v[e + 4] * xb[e];
    }
  }
  for (int m_ = 32; m_; m_ >>= 1) { a1 += __shfl_xor(a1, m_); a2 += __shfl_xor(a2, m_); }
  if (lane == 0) { pg1[row] = a1; pg2[row] = a2; }
}

// heads: m-part, writes final output rows
__global__ __launch_bounds__(256) void k_headsm(
    const bf16_t* __restrict__ m, const float* __restrict__ wm,
    const float* __restrict__ pg, const float* __restrict__ bg,
    const float* __restrict__ bm, float* __restrict__ out)
{
  int row  = blockIdx.x * 4 + (threadIdx.x >> 6);  // 0..12287
  int lane = threadIdx.x & 63;
  float a = 0.f;
  const bf16_t* mr = m + (long)row * 1536;
  for (int k = lane * 8; k < 1536; k += 512) {
    bf16x8 v = *(const bf16x8*)(mr + k);
    f32x4 wa = *(const f32x4*)(wm + k), wb = *(const f32x4*)(wm + k + 4);
    #pragma unroll
    for (int e = 0; e < 4; e++) a += (float)v[e] * wa[e] + (float)v[e + 4] * wb[e];
  }
  for (int m_ = 32; m_; m_ >>= 1) a += __shfl_xor(a, m_);
  if (lane == 0) out[row] = pg[row] + a + bg[0] + bm[0];
}

// ---------------------------------------------------------------------------

extern "C" void kernel_launch(void* const* d_in, const int* in_sizes, int n_in,
                              void* d_out, int out_size, void* d_ws, size_t ws_size,
                              hipStream_t stream)
{
  (void)in_sizes; (void)n_in; (void)out_size; (void)ws_size;
  const float* c    = (const float*)d_in[0];
  const float* q    = (const float*)d_in[1];
  const float* wac  = (const float*)d_in[2];
  const float* bac  = (const float*)d_in[3];
  const float* waq  = (const float*)d_in[4];
  const float* baq  = (const float*)d_in[5];
  const float* wacq = (const float*)d_in[6];
  const float* bacq = (const float*)d_in[7];
  const float* l1f_wih = (const float*)d_in[8];
  const float* l1f_whh = (const float*)d_in[9];
  const float* l1f_b   = (const float*)d_in[10];
  const float* l1b_wih = (const float*)d_in[11];
  const float* l1b_whh = (const float*)d_in[12];
  const float* l1b_b   = (const float*)d_in[13];
  const float* l2f_wih = (const float*)d_in[14];
  const float* l2f_whh = (const float*)d_in[15];
  const float* l2f_b   = (const float*)d_in[16];
  const float* l2b_wih = (const float*)d_in[17];
  const float* l2b_whh = (const float*)d_in[18];
  const float* l2b_b   = (const float*)d_in[19];
  const float* lof_wih = (const float*)d_in[20];
  const float* lof_whh = (const float*)d_in[21];
  const float* lof_b   = (const float*)d_in[22];
  const float* lob_wih = (const float*)d_in[23];
  const float* lob_whh = (const float*)d_in[24];
  const float* lob_b   = (const float*)d_in[25];
  const float* p1wg = (const float*)d_in[26];
  const float* p1bg = (const float*)d_in[27];
  const float* p1wm = (const float*)d_in[28];
  const float* p1bm = (const float*)d_in[29];
  const float* p2wg = (const float*)d_in[30];
  const float* p2bg = (const float*)d_in[31];
  const float* p2wm = (const float*)d_in[32];
  const float* p2bm = (const float*)d_in[33];

  // workspace layout (total ~227.6 MB)
  char* ws = (char*)d_ws;
  bf16_t* g_bf = (bf16_t*)ws;                       // [0, 75.5MB) g
  bf16_t* mA   = (bf16_t*)ws;                       // aliases g (g dead by stage1 lstm)
  bf16_t* mB   = (bf16_t*)(ws + 37748736L);         // second half of g region
  bf16_t* m2   = (bf16_t*)ws;                       // aliases mA (dead after stage2 GEMM)
  char*   xgc  = ws + 75497472L;                    // [75.5MB, 226.5MB) xg
  bf16_t* xg   = (bf16_t*)xgc;
  // attention temps alias the xg region (dead before stage1 GEMM writes xg)
  bf16_t* cw  = (bf16_t*)xgc;                       // 18,874,368
  bf16_t* qb  = (bf16_t*)(xgc + 18874368L);         //  3,145,728
  bf16_t* qT  = (bf16_t*)(xgc + 22020096L);         //  3,145,728
  float*  sS  = (float*) (xgc + 25165824L);         //  3,145,728
  bf16_t* aP  = (bf16_t*)(xgc + 28311552L);         //  1,572,864
  bf16_t* c2q = (bf16_t*)(xgc + 29884416L);         // 18,874,368
  char* tail = ws + 226492416L;
  float*    projc = (float*)tail;                   // 49,152
  float*    projq = (float*)(tail + 49152);         //  8,192
  float*    smax  = (float*)(tail + 57344);         // 49,152
  float*    bw    = (float*)(tail + 106496);        // 49,152
  float*    q2c   = (float*)(tail + 155648);        // 98,304
  float*    pg1   = (float*)(tail + 253952);        // 49,152
  float*    pg2   = (float*)(tail + 303104);        // 49,152
  unsigned* E     = (unsigned*)(tail + 352256);     // 2par x 2dir x 32 x 768 x 4B = 786,432

  k_zeroE<<<768, 256, 0, stream>>>(E);

  // ---- attention ----
  k_pack<<<43008, 256, 0, stream>>>(c, q, wacq, cw, qb);
  k_proj<<<3584, 256, 0, stream>>>(c, q, wac, bac, waq, baq, projc, projq);
  k_gemm<64,1,0><<<dim3(3,1,32), 256, 0, stream>>>(cw, qb, nullptr, 1<<30, sS,
      384, 64, 768, (long)384*768, (long)64*768, (long)384*64, projc, projq, bacq);
  k_smax_j<<<3072, 256, 0, stream>>>(sS, aP, smax);
  k_smax_i<<<32, 384, 0, stream>>>(smax, bw);
  k_q2c<<<dim3(3,32), 256, 0, stream>>>(bw, c, q2c);
  k_tq<<<dim3(12,32), 256, 0, stream>>>(qb, qT);
  k_gemm<64,0,0><<<dim3(3,12,32), 256, 0, stream>>>(aP, qT, nullptr, 1<<30, c2q,
      384, 768, 64, (long)384*64, (long)768*64, (long)384*768, nullptr, nullptr, nullptr);
  k_buildg<<<36864, 256, 0, stream>>>(c, c2q, q2c, g_bf);
  k_headsg<<<3072, 256, 0, stream>>>(g_bf, p1wg, p2wg, pg1, pg2);

  // ---- stage 1 (input 4H=3072) ----
  k_gemm<128,0,1><<<dim3(96,48,1), 256, 0, stream>>>(g_bf, l1f_wih, l1b_wih, 3072, xg,
      12288, 6144, 3072, 0, 0, 0, nullptr, nullptr, nullptr);
  k_lstm<<<48, 1024, 0, stream>>>(xg, mA, E, l1f_whh, l1b_whh, l1f_b, l1b_b, 0);

  // ---- stage 2 (input 2H=1536) ----
  k_gemm<128,0,1><<<dim3(96,48,1), 256, 0, stream>>>(mA, l2f_wih, l2b_wih, 3072, xg,
      12288, 6144, 1536, 0, 0, 0, nullptr, nullptr, nullptr);
  k_lstm<<<48, 1024, 0, stream>>>(xg, mB, E, l2f_whh, l2b_whh, l2f_b, l2b_b, 384);
  k_headsm<<<3072, 256, 0, stream>>>(mB, p1wm, pg1, p1bg, p1bm, (float*)d_out);

  // ---- stage 3 (output LSTM, input 2H=1536) ----
  k_gemm<128,0,1><<<dim3(96,48,1), 256, 0, stream>>>(mB, lof_wih, lob_wih, 3072, xg,
      12288, 6144, 1536, 0, 0, 0, nullptr, nullptr, nullptr);
  k_lstm<<<48, 1024, 0, stream>>>(xg, m2, E, lof_whh, lob_whh, lof_b, lob_b, 768);
  k_headsm<<<3072, 256, 0, stream>>>(m2, p2wm, pg2, p2bg, p2bm, (float*)d_out + 12288);
}

// Round 5
// 8309.609 us; speedup vs baseline: 1.2833x; 1.2645x over previous
//
#include <hip/hip_runtime.h>

// ---------------------------------------------------------------------------
// BiDAF block: B=32, CLEN=384, QLEN=64, H=768
// Workspace layout (~228MB):
//   [0, 75.5MB)    g  (later: mA @0, mB @37.7MB, m2 @0)
//   [75.5, 226.5)  xg (attention temps alias the front of this region)
//   [226.5, +)     tail scalars + E exchange buffer (~200KB)
// R6 geometry (proven: 104 VGPR, no spill): grid 96 = dir(2) x slice(24) x
// bg(2), 512 threads, wave = gate x col-half, whh tile in VGPRs (96/lane).
// R7 (4-phase interleave) REGRESSED: rendezvous cost is paid per rendezvous.
// R8 (1024 thr) REGRESSED: launch_bounds forced 64 VGPR -> weight spill.
// R9: sentinel handshake. Producers store UNTAGGED bf16 h pairs (relaxed
// AGENT atomics), per-wave s_waitcnt vmcnt(0), then lane0 posts ONE sentinel
// dword {tag} per (block,wave). Consumers spin on 192 sentinel dwords/chain
// (~768B/round, was 48KB/round of tagged data) and then bulk-read h ONCE
// (6 qword atomic loads/thread, was 12). Parity double-buffered.
// Liveness: every block is producer AND consumer of its chain and the spin
// covers its own waves' sentinels, so no slot can skip past a live spinner's
// wanted tag. R9b: s_sleep backoff in the spin (LLC-contention relief only;
// protocol unchanged). Previous submission died to an infra container flake.
// ---------------------------------------------------------------------------

typedef __bf16 bf16_t;
typedef __bf16 bf16x4 __attribute__((ext_vector_type(4)));
typedef __bf16 bf16x8 __attribute__((ext_vector_type(8)));
typedef float  f32x4  __attribute__((ext_vector_type(4)));
typedef unsigned long long ull;

#define TT 384

__device__ __forceinline__ void gload_lds16(const void* g, void* l) {
  __builtin_amdgcn_global_load_lds((const __attribute__((address_space(1))) void*)g,
                                   (__attribute__((address_space(3))) void*)l, 16, 0, 0);
}

// workgroup barrier ordering LDS only: does NOT drain vmcnt, so global loads
// issued earlier stay in flight across it (unlike __syncthreads()).
__device__ __forceinline__ void wg_barrier_lds() {
  asm volatile("s_waitcnt lgkmcnt(0)" ::: "memory");
  __builtin_amdgcn_s_barrier();
  asm volatile("" ::: "memory");
}

// init sentinel dwords to 0xFFFFFFFF (never matches a wanted tag in [0,1152))
__global__ void k_zeroE(unsigned* p) {
  int i = blockIdx.x * 256 + threadIdx.x;
  __hip_atomic_store(p + i, 0xFFFFFFFFu, __ATOMIC_RELAXED, __HIP_MEMORY_SCOPE_AGENT);
}

// ---------------------------------------------------------------------------
// GEMM: C[M,N] = A[M,K] * B[N,K]^T, A bf16 K-contig (global_load_lds).
// BSRC=0: B bf16 via global_load_lds (Bv + bz*sBb). BSRC=1: B fp32 from
// Bv (rows < nsplit) / Bv2 (rows >= nsplit), converted during staging.
// BM=128, BK=32, 256 threads = 4 waves (2x2), wave tile 64 x (BN/2).
// EPI=0: bf16 out. EPI=1: f32 out + rowb[bz*M+row] + colb[bz*N+col] + *sb.
// ---------------------------------------------------------------------------
template<int BN, int EPI, int BSRC>
__global__ __launch_bounds__(256) void k_gemm(
    const bf16_t* __restrict__ A, const void* __restrict__ Bv, const void* __restrict__ Bv2,
    int nsplit, void* __restrict__ Cv,
    int M, int N, int K, long sAb, long sBb, long sCb,
    const float* __restrict__ rowb, const float* __restrict__ colb,
    const float* __restrict__ sb)
{
  constexpr int BM = 128, BK = 32;
  constexpr int NT = BN / 32;          // 16-wide N tiles per wave
  __shared__ bf16_t sA[BM * BK];
  __shared__ bf16_t sB[BN * BK];
  const int t    = threadIdx.x;
  const int lane = t & 63;
  const int wm   = (t >> 6) >> 1, wn = (t >> 6) & 1;
  const long bz  = blockIdx.z;
  const int nbase = blockIdx.y * BN;
  const bf16_t* Ab = A + bz * sAb + (long)blockIdx.x * BM * K;
  const bf16_t* Bb = nullptr;
  const float*  Bf = nullptr;
  if constexpr (BSRC == 0)
    Bb = (const bf16_t*)Bv + bz * sBb + (long)nbase * K;
  else
    Bf = (nbase < nsplit) ? ((const float*)Bv  + (long)nbase * K)
                          : ((const float*)Bv2 + (long)(nbase - nsplit) * K);

  const int r4 = t >> 2;                          // staging row 0..63
  const int kq = (t & 3) ^ ((r4 >> 1) & 3);       // XOR-swizzled source k-quad

  f32x4 acc[4][NT];
  #pragma unroll
  for (int i = 0; i < 4; i++)
    #pragma unroll
    for (int j = 0; j < NT; j++) acc[i][j] = (f32x4){0.f, 0.f, 0.f, 0.f};

  const int mrow = lane & 15;
  const int fq   = lane >> 4;
  const int aswz = (fq ^ ((mrow >> 1) & 3)) * 8;  // swizzled frag k-offset (elems)

  for (int k0 = 0; k0 < K; k0 += BK) {
    __syncthreads();
    gload_lds16(Ab + (long)r4 * K + k0 + kq * 8,        (char*)sA + t * 16);
    gload_lds16(Ab + (long)(64 + r4) * K + k0 + kq * 8, (char*)sA + 4096 + t * 16);
    if constexpr (BSRC == 0) {
      gload_lds16(Bb + (long)r4 * K + k0 + kq * 8,        (char*)sB + t * 16);
      if constexpr (BN == 128)
        gload_lds16(Bb + (long)(64 + r4) * K + k0 + kq * 8, (char*)sB + 4096 + t * 16);
    } else {
      {
        f32x4 b0 = *(const f32x4*)(Bf + (long)r4 * K + k0 + kq * 8);
        f32x4 b1 = *(const f32x4*)(Bf + (long)r4 * K + k0 + kq * 8 + 4);
        bf16x8 bb;
        #pragma unroll
        for (int e = 0; e < 4; e++) { bb[e] = (bf16_t)b0[e]; bb[e + 4] = (bf16_t)b1[e]; }
        *(bf16x8*)((char*)sB + t * 16) = bb;
      }
      if constexpr (BN == 128) {
        f32x4 b0 = *(const f32x4*)(Bf + (long)(64 + r4) * K + k0 + kq * 8);
        f32x4 b1 = *(const f32x4*)(Bf + (long)(64 + r4) * K + k0 + kq * 8 + 4);
        bf16x8 bb;
        #pragma unroll
        for (int e = 0; e < 4; e++) { bb[e] = (bf16_t)b0[e]; bb[e + 4] = (bf16_t)b1[e]; }
        *(bf16x8*)((char*)sB + 4096 + t * 16) = bb;
      }
    }
    __syncthreads();

    bf16x8 af[4], bv[NT];
    #pragma unroll
    for (int mt = 0; mt < 4; mt++)
      af[mt] = *(const bf16x8*)(sA + (wm * 64 + mt * 16 + mrow) * 32 + aswz);
    #pragma unroll
    for (int nt = 0; nt < NT; nt++)
      bv[nt] = *(const bf16x8*)(sB + (wn * (BN / 2) + nt * 16 + mrow) * 32 + aswz);
    #pragma unroll
    for (int mt = 0; mt < 4; mt++)
      #pragma unroll
      for (int nt = 0; nt < NT; nt++)
        acc[mt][nt] = __builtin_amdgcn_mfma_f32_16x16x32_bf16(af[mt], bv[nt], acc[mt][nt], 0, 0, 0);
  }

  const int rbase = (lane >> 4) * 4;
  #pragma unroll
  for (int mt = 0; mt < 4; mt++)
    #pragma unroll
    for (int nt = 0; nt < NT; nt++)
      #pragma unroll
      for (int r = 0; r < 4; r++) {
        int grow = blockIdx.x * BM + wm * 64 + mt * 16 + rbase + r;
        int gcol = nbase + wn * (BN / 2) + nt * 16 + (lane & 15);
        if constexpr (EPI == 0) {
          ((bf16_t*)Cv)[bz * sCb + (long)grow * N + gcol] = (bf16_t)acc[mt][nt][r];
        } else {
          ((float*)Cv)[bz * sCb + (long)grow * N + gcol] =
              acc[mt][nt][r] + rowb[bz * M + grow] + colb[bz * N + gcol] + sb[0];
        }
      }
}

// ---------------------------------------------------------------------------
// Recurrent biLSTM stage. grid = 96: dir(2) x slice(24) x bg(2), 512 threads
// = 8 waves, wave w: gate g = w&3, col-half ch = w>>2. whh tile (16 cols) in
// VGPRs (24 x bf16x8 = 96 VGPR/lane). LDS: sH (h staging, 776-elem padded
// rows) + sG (gate exchange, stride-17 padded).
// Exchange (R9): E = [sentinels: 2par x 2dir x 2bg x 24sl x 8w dwords]
//                    [data: 2par x 2dir x 32b x 768col bf16, untagged]
// Producer wave: paired-dword h stores (relaxed AGENT) -> s_waitcnt vmcnt(0)
// (wave-scope, covers all lanes) -> lane0 posts sentinel {tagbase+s}.
// Consumer: every wave spins on the chain's 192 sentinels (3 dwords/lane),
// then bulk-reads h once (6 qword relaxed atomic loads/thread) into sH.
// Safety: sentinel(s) from wave W implies W's step-(s-1) reads completed
// (vmcnt(0) drains loads too), so a parity slot has no in-flight readers
// when overwritten (standard induction; every block is in its own spin set).
// mout: [B, T, 2H] bf16 (fwd | bwd) — plain paired stores.
// ---------------------------------------------------------------------------
__global__ __launch_bounds__(512) void k_lstm(
    const bf16_t* __restrict__ xg, bf16_t* __restrict__ mout,
    unsigned* __restrict__ E,
    const float* __restrict__ whh_f, const float* __restrict__ whh_b,
    const float* __restrict__ bias_f, const float* __restrict__ bias_b,
    int tagbase)
{
  __shared__ bf16_t sH[16 * 776];   // 24,832 B
  __shared__ float  sG[4 * 272];    //  4,352 B => 29,184 B total
  const int t    = threadIdx.x;
  const int lane = t & 63;
  const int w    = t >> 6;                 // wave 0..7
  const int g    = w & 3;                  // gate
  const int ch   = w >> 2;                 // col half (16-col tile)
  const int blk  = blockIdx.x;
  const int dir  = blk / 48;
  const int qq   = blk - dir * 48;
  const int sl   = qq >> 1;                // slice 0..23
  const int bg   = qq & 1;                 // batch group 0..1
  const int j0   = sl * 32;
  const float* whh  = dir ? whh_b : whh_f;
  const float* bias = dir ? bias_b : bias_f;

  const int mrow = lane & 15;
  const int fq   = lane >> 4;

  unsigned* Es = E;                        // 1536 sentinel dwords
  unsigned* Ed = E + 1536;                 // data: 2x2x32x768 bf16

  // stage this wave's whh tile into registers (B operand), f32 -> bf16.
  // lane (mrow,fq) holds whh[g*768 + j0 + ch*16 + mrow][kc*32 + fq*8 .. +8]
  bf16x8 bw[24];
  {
    const float* wrow = whh + (long)(g * 768 + j0 + ch * 16 + mrow) * 768 + fq * 8;
    #pragma unroll
    for (int kc = 0; kc < 24; kc++) {
      f32x4 v0 = *(const f32x4*)(wrow + kc * 32);
      f32x4 v1 = *(const f32x4*)(wrow + kc * 32 + 4);
      bf16x8 bb;
      #pragma unroll
      for (int e = 0; e < 4; e++) { bb[e] = (bf16_t)v0[e]; bb[e + 4] = (bf16_t)v1[e]; }
      bw[kc] = bb;
    }
  }

  const int b16 = t >> 5;                  // local batch 0..15 (wave w: 2w,2w+1)
  const int jj  = t & 31;                  // local col 0..31
  float bsv[4];
  #pragma unroll
  for (int gi = 0; gi < 4; gi++) bsv[gi] = bias[gi * 768 + j0 + jj];

  // loop-invariant consumer offsets: e = i*512+t covers 16 batches x 192
  // qwords (768 cols x 2B = 1536 B = 192 qwords per batch row)
  int soff[6];
  #pragma unroll
  for (int i = 0; i < 6; i++) {
    int e = i * 512 + t;
    soff[i] = (e / 192) * 1552 + (e % 192) * 8;  // sH byte offset (4 bf16/qword)
  }

  float cst = 0.f;
  const int aoff0 = mrow * 776 + fq * 8;
  const long xrow0 = (long)(bg * 16 + b16) * TT;

  for (int s = 0; s < TT; s++) {
    const int tc = dir ? (TT - 1 - s) : s;

    if (s == 0) {
      for (int e = t; e < 1552; e += 512)
        *(f32x4*)((char*)sH + e * 16) = (f32x4){0.f, 0.f, 0.f, 0.f};
    } else {
      const unsigned want = (unsigned)(tagbase + s - 1);
      const int par = (s - 1) & 1;
      // 1) spin on the chain's 192 sentinels (every wave, independently).
      // s_sleep backoff relieves LLC-line contention; protocol unchanged.
      {
        const unsigned* sp = Es + ((par * 2 + dir) * 2 + bg) * 192;
        for (;;) {
          unsigned s0 = __hip_atomic_load(sp + lane,       __ATOMIC_RELAXED, __HIP_MEMORY_SCOPE_AGENT);
          unsigned s1 = __hip_atomic_load(sp + 64 + lane,  __ATOMIC_RELAXED, __HIP_MEMORY_SCOPE_AGENT);
          unsigned s2 = __hip_atomic_load(sp + 128 + lane, __ATOMIC_RELAXED, __HIP_MEMORY_SCOPE_AGENT);
          if (__all(s0 == want && s1 == want && s2 == want)) break;
          __builtin_amdgcn_s_sleep(1);
        }
      }
      asm volatile("" ::: "memory");
      // 2) bulk-read h once (atomic loads bypass stale L1/L2 to LLC)
      {
        const ull* dq = (const ull*)Ed + ((long)(par * 2 + dir) * 32 + bg * 16) * 192;
        ull qv[6];
        #pragma unroll
        for (int i = 0; i < 6; i++)
          qv[i] = __hip_atomic_load(dq + i * 512 + t, __ATOMIC_RELAXED, __HIP_MEMORY_SCOPE_AGENT);
        #pragma unroll
        for (int i = 0; i < 6; i++)
          *(ull*)((char*)sH + soff[i]) = qv[i];
      }
    }

    // xg gate values (issued after bulk loads; consumed after MFMA)
    float xv[4];
    {
      long xr = (xrow0 + tc) * 6144 + dir * 3072 + j0 + jj;
      #pragma unroll
      for (int gi = 0; gi < 4; gi++) xv[gi] = (float)xg[xr + gi * 768];
    }

    wg_barrier_lds();

    // two independent 12-deep accumulate chains over K=768
    f32x4 a0 = (f32x4){0.f, 0.f, 0.f, 0.f};
    f32x4 a1 = (f32x4){0.f, 0.f, 0.f, 0.f};
    #pragma unroll
    for (int kc = 0; kc < 24; kc += 2) {
      bf16x8 av0 = *(const bf16x8*)(sH + aoff0 + kc * 32);
      bf16x8 av1 = *(const bf16x8*)(sH + aoff0 + kc * 32 + 32);
      a0 = __builtin_amdgcn_mfma_f32_16x16x32_bf16(av0, bw[kc],     a0, 0, 0, 0);
      a1 = __builtin_amdgcn_mfma_f32_16x16x32_bf16(av1, bw[kc + 1], a1, 0, 0, 0);
    }
    #pragma unroll
    for (int r = 0; r < 4; r++)
      sG[g * 272 + (ch * 16 + mrow) * 17 + fq * 4 + r] = a0[r] + a1[r];
    wg_barrier_lds();

    {
      float gv0 = sG[0 * 272 + jj * 17 + b16] + xv[0] + bsv[0];
      float gv1 = sG[1 * 272 + jj * 17 + b16] + xv[1] + bsv[1];
      float gv2 = sG[2 * 272 + jj * 17 + b16] + xv[2] + bsv[2];
      float gv3 = sG[3 * 272 + jj * 17 + b16] + xv[3] + bsv[3];
      gv0 = 1.f / (1.f + __expf(-gv0));
      gv1 = 1.f / (1.f + __expf(-gv1));
      gv2 = 1.f - 2.f / (__expf(2.f * gv2) + 1.f);
      gv3 = 1.f / (1.f + __expf(-gv3));
      cst = gv1 * cst + gv0 * gv2;
      float hv = gv3 * (1.f - 2.f / (__expf(2.f * cst) + 1.f));
      union { bf16_t b; unsigned short u; } pk;
      pk.b = (bf16_t)hv;
      unsigned myd = (unsigned)pk.u;
      unsigned od  = (unsigned)__shfl_xor((int)myd, 1);   // partner col's h
      if ((t & 1) == 0) {
        unsigned mo = myd | (od << 16);
        long di = ((long)((s & 1) * 2 + dir) * 32 + bg * 16 + b16) * 768 + j0 + jj;
        __hip_atomic_store(Ed + (di >> 1), mo,
                           __ATOMIC_RELAXED, __HIP_MEMORY_SCOPE_AGENT);
        *(unsigned*)(mout + (xrow0 + tc) * 1536 + dir * 768 + j0 + jj) = mo;
      }
    }
    // wave-scope drain: all 64 lanes' data stores reached the LLC, then post
    // this wave's sentinel. No block barrier needed (per-wave granularity).
    asm volatile("s_waitcnt vmcnt(0)" ::: "memory");
    if (lane == 0) {
      __hip_atomic_store(Es + (((s & 1) * 2 + dir) * 2 + bg) * 192 + sl * 8 + w,
                         (unsigned)(tagbase + s),
                         __ATOMIC_RELAXED, __HIP_MEMORY_SCOPE_AGENT);
    }
    // no end-of-step barrier: next iteration's sH overwrite is fenced by the
    // second wg_barrier (all waves passed their MFMA sH reads by then)
  }
}

// --------------------------- attention helpers -----------------------------

__global__ __launch_bounds__(256) void k_pack(
    const float* __restrict__ c, const float* __restrict__ q,
    const float* __restrict__ wcq, bf16_t* __restrict__ cw, bf16_t* __restrict__ qb)
{
  int i = blockIdx.x * 256 + threadIdx.x;        // 43008 blocks -> 11,010,048
  if (i < 9437184) {
    int h = i % 768;
    cw[i] = (bf16_t)(c[i] * wcq[h]);
  } else {
    int j = i - 9437184;
    qb[j] = (bf16_t)q[j];
  }
}

__global__ __launch_bounds__(256) void k_proj(
    const float* __restrict__ c, const float* __restrict__ q,
    const float* __restrict__ wc, const float* __restrict__ bc,
    const float* __restrict__ wq, const float* __restrict__ bq,
    float* __restrict__ projc, float* __restrict__ projq)
{
  int row  = blockIdx.x * 4 + (threadIdx.x >> 6);  // 0..14335
  int lane = threadIdx.x & 63;
  const float *src, *w;
  bool isC = row < 12288;
  if (isC) { src = c + (long)row * 768;          w = wc; }
  else     { src = q + (long)(row - 12288) * 768; w = wq; }
  float a = 0.f;
  for (int k = lane * 4; k < 768; k += 256) {
    f32x4 v = *(const f32x4*)(src + k);
    f32x4 wv = *(const f32x4*)(w + k);
    a += v[0]*wv[0] + v[1]*wv[1] + v[2]*wv[2] + v[3]*wv[3];
  }
  for (int m = 32; m; m >>= 1) a += __shfl_xor(a, m);
  if (lane == 0) {
    if (isC) projc[row] = a + bc[0];
    else     projq[row - 12288] = a + bq[0];
  }
}

__global__ __launch_bounds__(256) void k_smax_j(
    const float* __restrict__ s, bf16_t* __restrict__ a, float* __restrict__ smax)
{
  int row  = blockIdx.x * 4 + (threadIdx.x >> 6);
  int lane = threadIdx.x & 63;
  float v = s[(long)row * 64 + lane];
  float mx = v;
  for (int m = 32; m; m >>= 1) mx = fmaxf(mx, __shfl_xor(mx, m));
  float p = __expf(v - mx);
  float sum = p;
  for (int m = 32; m; m >>= 1) sum += __shfl_xor(sum, m);
  a[(long)row * 64 + lane] = (bf16_t)(p / sum);
  if (lane == 0) smax[row] = mx;
}

__global__ __launch_bounds__(384) void k_smax_i(
    const float* __restrict__ smax, float* __restrict__ bw)
{
  __shared__ float red[8];
  int b = blockIdx.x, t = threadIdx.x;   // 384 threads, 6 waves
  int lane = t & 63, wv = t >> 6;
  float v = smax[b * 384 + t];
  float mx = v;
  for (int m = 32; m; m >>= 1) mx = fmaxf(mx, __shfl_xor(mx, m));
  if (lane == 0) red[wv] = mx;
  __syncthreads();
  float gm = red[0];
  #pragma unroll
  for (int i = 1; i < 6; i++) gm = fmaxf(gm, red[i]);
  float p = __expf(v - gm);
  float sm = p;
  for (int m = 32; m; m >>= 1) sm += __shfl_xor(sm, m);
  __syncthreads();
  if (lane == 0) red[wv] = sm;
  __syncthreads();
  float tot = red[0];
  #pragma unroll
  for (int i = 1; i < 6; i++) tot += red[i];
  bw[b * 384 + t] = p / tot;
}

__global__ __launch_bounds__(256) void k_q2c(
    const float* __restrict__ bw, const float* __restrict__ c, float* __restrict__ q2c)
{
  int b = blockIdx.y;
  int h = blockIdx.x * 256 + threadIdx.x;
  const float* cb = c + (long)b * 384 * 768;
  float acc = 0.f;
  for (int i = 0; i < 384; i++) acc += bw[b * 384 + i] * cb[(long)i * 768 + h];
  q2c[b * 768 + h] = acc;
}

__global__ __launch_bounds__(256) void k_tq(
    const bf16_t* __restrict__ qb, bf16_t* __restrict__ qT)
{
  __shared__ bf16_t sT[64][72];
  int b = blockIdx.y, hc = blockIdx.x, t = threadIdx.x;
  {
    int j = t >> 2, h0 = (t & 3) * 16;
    const bf16_t* src = qb + (long)(b * 64 + j) * 768 + hc * 64 + h0;
    *(bf16x8*)&sT[j][h0]     = *(const bf16x8*)(src);
    *(bf16x8*)&sT[j][h0 + 8] = *(const bf16x8*)(src + 8);
  }
  __syncthreads();
  {
    int h = t >> 2, j0 = (t & 3) * 16;
    bf16x8 o0, o1;
    #pragma unroll
    for (int e = 0; e < 8; e++) { o0[e] = sT[j0 + e][h]; o1[e] = sT[j0 + 8 + e][h]; }
    bf16_t* dst = qT + (long)(b * 768 + hc * 64 + h) * 64 + j0;
    *(bf16x8*)dst       = o0;
    *(bf16x8*)(dst + 8) = o1;
  }
}

__global__ __launch_bounds__(256) void k_buildg(
    const float* __restrict__ c, const bf16_t* __restrict__ c2q,
    const float* __restrict__ q2c, bf16_t* __restrict__ g)
{
  int i = blockIdx.x * 256 + threadIdx.x;   // < 9,437,184
  int h = i % 768;
  int row = i / 768;
  int b = row / 384;
  float cv  = c[i];
  float cqv = (float)c2q[i];
  float qcv = q2c[b * 768 + h];
  bf16_t* gr = g + (long)row * 3072;
  gr[h]        = (bf16_t)cv;
  gr[768 + h]  = c2q[i];
  gr[1536 + h] = (bf16_t)(cv * cqv);
  gr[2304 + h] = (bf16_t)(cv * qcv);
}

// heads: g-part (both p1 and p2), one pass over g
__global__ __launch_bounds__(256) void k_headsg(
    const bf16_t* __restrict__ g, const float* __restrict__ w1, const float* __restrict__ w2,
    float* __restrict__ pg1, float* __restrict__ pg2)
{
  int row  = blockIdx.x * 4 + (threadIdx.x >> 6);  // 0..12287
  int lane = threadIdx.x & 63;
  float a1 = 0.f, a2 = 0.f;
  const bf16_t* gr = g + (long)row * 3072;
  for (int k = lane * 8; k < 3072; k += 512) {
    bf16x8 v = *(const bf16x8*)(gr + k);
    f32x4 wa = *(const f32x4*)(w1 + k), wb = *(const f32x4*)(w1 + k + 4);
    f32x4 xa = *(const f32x4*)(w2 + k), xb = *(const f32x4*)(w2 + k + 4);
    #pragma unroll
    for (int e = 0; e < 4; e++) {
      a1 += (float)v[e] * wa[e] + (float)v[e + 4] * wb[e];
      a2 += (float)v[e] * xa[e] + (float)v[e + 4] * xb[e];
    }
  }
  for (int m_ = 32; m_; m_ >>= 1) { a1 += __shfl_xor(a1, m_); a2 += __shfl_xor(a2, m_); }
  if (lane == 0) { pg1[row] = a1; pg2[row] = a2; }
}

// heads: m-part, writes final output rows
__global__ __launch_bounds__(256) void k_headsm(
    const bf16_t* __restrict__ m, const float* __restrict__ wm,
    const float* __restrict__ pg, const float* __restrict__ bg,
    const float* __restrict__ bm, float* __restrict__ out)
{
  int row  = blockIdx.x * 4 + (threadIdx.x >> 6);  // 0..12287
  int lane = threadIdx.x & 63;
  float a = 0.f;
  const bf16_t* mr = m + (long)row * 1536;
  for (int k = lane * 8; k < 1536; k += 512) {
    bf16x8 v = *(const bf16x8*)(mr + k);
    f32x4 wa = *(const f32x4*)(wm + k), wb = *(const f32x4*)(wm + k + 4);
    #pragma unroll
    for (int e = 0; e < 4; e++) a += (float)v[e] * wa[e] + (float)v[e + 4] * wb[e];
  }
  for (int m_ = 32; m_; m_ >>= 1) a += __shfl_xor(a, m_);
  if (lane == 0) out[row] = pg[row] + a + bg[0] + bm[0];
}

// ---------------------------------------------------------------------------

extern "C" void kernel_launch(void* const* d_in, const int* in_sizes, int n_in,
                              void* d_out, int out_size, void* d_ws, size_t ws_size,
                              hipStream_t stream)
{
  (void)in_sizes; (void)n_in; (void)out_size; (void)ws_size;
  const float* c    = (const float*)d_in[0];
  const float* q    = (const float*)d_in[1];
  const float* wac  = (const float*)d_in[2];
  const float* bac  = (const float*)d_in[3];
  const float* waq  = (const float*)d_in[4];
  const float* baq  = (const float*)d_in[5];
  const float* wacq = (const float*)d_in[6];
  const float* bacq = (const float*)d_in[7];
  const float* l1f_wih = (const float*)d_in[8];
  const float* l1f_whh = (const float*)d_in[9];
  const float* l1f_b   = (const float*)d_in[10];
  const float* l1b_wih = (const float*)d_in[11];
  const float* l1b_whh = (const float*)d_in[12];
  const float* l1b_b   = (const float*)d_in[13];
  const float* l2f_wih = (const float*)d_in[14];
  const float* l2f_whh = (const float*)d_in[15];
  const float* l2f_b   = (const float*)d_in[16];
  const float* l2b_wih = (const float*)d_in[17];
  const float* l2b_whh = (const float*)d_in[18];
  const float* l2b_b   = (const float*)d_in[19];
  const float* lof_wih = (const float*)d_in[20];
  const float* lof_whh = (const float*)d_in[21];
  const float* lof_b   = (const float*)d_in[22];
  const float* lob_wih = (const float*)d_in[23];
  const float* lob_whh = (const float*)d_in[24];
  const float* lob_b   = (const float*)d_in[25];
  const float* p1wg = (const float*)d_in[26];
  const float* p1bg = (const float*)d_in[27];
  const float* p1wm = (const float*)d_in[28];
  const float* p1bm = (const float*)d_in[29];
  const float* p2wg = (const float*)d_in[30];
  const float* p2bg = (const float*)d_in[31];
  const float* p2wm = (const float*)d_in[32];
  const float* p2bm = (const float*)d_in[33];

  // workspace layout (total ~227.6 MB)
  char* ws = (char*)d_ws;
  bf16_t* g_bf = (bf16_t*)ws;                       // [0, 75.5MB) g
  bf16_t* mA   = (bf16_t*)ws;                       // aliases g (g dead by stage1 lstm)
  bf16_t* mB   = (bf16_t*)(ws + 37748736L);         // second half of g region
  bf16_t* m2   = (bf16_t*)ws;                       // aliases mA (dead after stage2 GEMM)
  char*   xgc  = ws + 75497472L;                    // [75.5MB, 226.5MB) xg
  bf16_t* xg   = (bf16_t*)xgc;
  // attention temps alias the xg region (dead before stage1 GEMM writes xg)
  bf16_t* cw  = (bf16_t*)xgc;                       // 18,874,368
  bf16_t* qb  = (bf16_t*)(xgc + 18874368L);         //  3,145,728
  bf16_t* qT  = (bf16_t*)(xgc + 22020096L);         //  3,145,728
  float*  sS  = (float*) (xgc + 25165824L);         //  3,145,728
  bf16_t* aP  = (bf16_t*)(xgc + 28311552L);         //  1,572,864
  bf16_t* c2q = (bf16_t*)(xgc + 29884416L);         // 18,874,368
  char* tail = ws + 226492416L;
  float*    projc = (float*)tail;                   // 49,152
  float*    projq = (float*)(tail + 49152);         //  8,192
  float*    smax  = (float*)(tail + 57344);         // 49,152
  float*    bw    = (float*)(tail + 106496);        // 49,152
  float*    q2c   = (float*)(tail + 155648);        // 98,304
  float*    pg1   = (float*)(tail + 253952);        // 49,152
  float*    pg2   = (float*)(tail + 303104);        // 49,152
  unsigned* E     = (unsigned*)(tail + 352256);     // 1536 sentinel dw + 196,608B data

  k_zeroE<<<6, 256, 0, stream>>>(E);   // init the 1536 sentinel dwords

  // ---- attention ----
  k_pack<<<43008, 256, 0, stream>>>(c, q, wacq, cw, qb);
  k_proj<<<3584, 256, 0, stream>>>(c, q, wac, bac, waq, baq, projc, projq);
  k_gemm<64,1,0><<<dim3(3,1,32), 256, 0, stream>>>(cw, qb, nullptr, 1<<30, sS,
      384, 64, 768, (long)384*768, (long)64*768, (long)384*64, projc, projq, bacq);
  k_smax_j<<<3072, 256, 0, stream>>>(sS, aP, smax);
  k_smax_i<<<32, 384, 0, stream>>>(smax, bw);
  k_q2c<<<dim3(3,32), 256, 0, stream>>>(bw, c, q2c);
  k_tq<<<dim3(12,32), 256, 0, stream>>>(qb, qT);
  k_gemm<64,0,0><<<dim3(3,12,32), 256, 0, stream>>>(aP, qT, nullptr, 1<<30, c2q,
      384, 768, 64, (long)384*64, (long)768*64, (long)384*768, nullptr, nullptr, nullptr);
  k_buildg<<<36864, 256, 0, stream>>>(c, c2q, q2c, g_bf);
  k_headsg<<<3072, 256, 0, stream>>>(g_bf, p1wg, p2wg, pg1, pg2);

  // ---- stage 1 (input 4H=3072) ----
  k_gemm<128,0,1><<<dim3(96,48,1), 256, 0, stream>>>(g_bf, l1f_wih, l1b_wih, 3072, xg,
      12288, 6144, 3072, 0, 0, 0, nullptr, nullptr, nullptr);
  k_lstm<<<96, 512, 0, stream>>>(xg, mA, E, l1f_whh, l1b_whh, l1f_b, l1b_b, 0);

  // ---- stage 2 (input 2H=1536) ----
  k_gemm<128,0,1><<<dim3(96,48,1), 256, 0, stream>>>(mA, l2f_wih, l2b_wih, 3072, xg,
      12288, 6144, 1536, 0, 0, 0, nullptr, nullptr, nullptr);
  k_lstm<<<96, 512, 0, stream>>>(xg, mB, E, l2f_whh, l2b_whh, l2f_b, l2b_b, 384);
  k_headsm<<<3072, 256, 0, stream>>>(mB, p1wm, pg1, p1bg, p1bm, (float*)d_out);

  // ---- stage 3 (output LSTM, input 2H=1536) ----
  k_gemm<128,0,1><<<dim3(96,48,1), 256, 0, stream>>>(mB, lof_wih, lob_wih, 3072, xg,
      12288, 6144, 1536, 0, 0, 0, nullptr, nullptr, nullptr);
  k_lstm<<<96, 512, 0, stream>>>(xg, m2, E, lof_whh, lob_whh, lof_b, lob_b, 768);
  k_headsm<<<3072, 256, 0, stream>>>(m2, p2wm, pg2, p2bg, p2bm, (float*)d_out + 12288);
}

// Round 6
// 6380.429 us; speedup vs baseline: 1.6713x; 1.3024x over previous
//
#include <hip/hip_runtime.h>

// ---------------------------------------------------------------------------
// BiDAF block: B=32, CLEN=384, QLEN=64, H=768
// Workspace layout (~228MB):
//   [0, 75.5MB)    g  (later: mA @0, mB @37.7MB, m2 @0; B3 @0, B2 @37.7MB
//                     transiently during stage GEMMs — windows are dead then)
//   [75.5, 226.5)  xg (attention temps alias the front of this region)
//   [226.5, +)     tail scalars + E exchange buffer (786KB)
// k_lstm exchange (R5/R6, PROVEN BEST 1655us): tag-in-data dwords
// {tag:16|bf16 h:16} in LLC-resident E buffer, parity double-buffered;
// consumers poll data tags directly — the successful poll round IS the data
// transfer (one LLC trip/step). Ledger: R7 4-phase interleave 2989us
// (rendezvous cost is per-rendezvous); R8 1024thr 3008us (launch_bounds
// forced 64 VGPR -> weight spill); R9 sentinel handshake 2220us (split one
// trip into two serial trips). ~4.3us/step is the one-trip floor.
// R10: revert lstm to exact R6 protocol (xv issued post-poll; lgkm-only
// barriers so xv flies through MFMA). Stage GEMMs: pre-convert wih fp32->
// bf16 into dead windows and use global_load_lds for B (BSRC=0) instead of
// VALU staging (BSRC=1) — Common-mistake #1.
// ---------------------------------------------------------------------------

typedef __bf16 bf16_t;
typedef __bf16 bf16x4 __attribute__((ext_vector_type(4)));
typedef __bf16 bf16x8 __attribute__((ext_vector_type(8)));
typedef float  f32x4  __attribute__((ext_vector_type(4)));
typedef unsigned long long ull;

#define TT 384

__device__ __forceinline__ void gload_lds16(const void* g, void* l) {
  __builtin_amdgcn_global_load_lds((const __attribute__((address_space(1))) void*)g,
                                   (__attribute__((address_space(3))) void*)l, 16, 0, 0);
}

// workgroup barrier ordering LDS only: does NOT drain vmcnt, so global loads
// issued earlier (xv) stay in flight across it (unlike __syncthreads()).
__device__ __forceinline__ void wg_barrier_lds() {
  asm volatile("s_waitcnt lgkmcnt(0)" ::: "memory");
  __builtin_amdgcn_s_barrier();
  asm volatile("" ::: "memory");
}

// set all E tags to 0xFFFF (never matches a wanted tag in [0,1152))
__global__ void k_zeroE(unsigned* p) {
  int i = blockIdx.x * 256 + threadIdx.x;
  __hip_atomic_store(p + i, 0xFFFF0000u, __ATOMIC_RELAXED, __HIP_MEMORY_SCOPE_AGENT);
}

// convert wih fp32 (fwd rows then bwd rows) -> contiguous bf16 B matrix
__global__ __launch_bounds__(256) void k_cvtB(
    const float* __restrict__ wf, const float* __restrict__ wb,
    long half_elems, bf16_t* __restrict__ dst)
{
  long i = ((long)blockIdx.x * 256 + threadIdx.x) * 4;
  const float* src = (i < half_elems) ? wf + i : wb + (i - half_elems);
  f32x4 v = *(const f32x4*)src;
  bf16x4 o;
  o[0] = (bf16_t)v[0]; o[1] = (bf16_t)v[1]; o[2] = (bf16_t)v[2]; o[3] = (bf16_t)v[3];
  *(bf16x4*)(dst + i) = o;
}

// ---------------------------------------------------------------------------
// GEMM: C[M,N] = A[M,K] * B[N,K]^T, A bf16 K-contig (global_load_lds).
// BSRC=0: B bf16 via global_load_lds (Bv + bz*sBb). BSRC=1: B fp32 from
// Bv (rows < nsplit) / Bv2 (rows >= nsplit), converted during staging.
// BM=128, BK=32, 256 threads = 4 waves (2x2), wave tile 64 x (BN/2).
// EPI=0: bf16 out. EPI=1: f32 out + rowb[bz*M+row] + colb[bz*N+col] + *sb.
// ---------------------------------------------------------------------------
template<int BN, int EPI, int BSRC>
__global__ __launch_bounds__(256) void k_gemm(
    const bf16_t* __restrict__ A, const void* __restrict__ Bv, const void* __restrict__ Bv2,
    int nsplit, void* __restrict__ Cv,
    int M, int N, int K, long sAb, long sBb, long sCb,
    const float* __restrict__ rowb, const float* __restrict__ colb,
    const float* __restrict__ sb)
{
  constexpr int BM = 128, BK = 32;
  constexpr int NT = BN / 32;          // 16-wide N tiles per wave
  __shared__ bf16_t sA[BM * BK];
  __shared__ bf16_t sB[BN * BK];
  const int t    = threadIdx.x;
  const int lane = t & 63;
  const int wm   = (t >> 6) >> 1, wn = (t >> 6) & 1;
  const long bz  = blockIdx.z;
  const int nbase = blockIdx.y * BN;
  const bf16_t* Ab = A + bz * sAb + (long)blockIdx.x * BM * K;
  const bf16_t* Bb = nullptr;
  const float*  Bf = nullptr;
  if constexpr (BSRC == 0)
    Bb = (const bf16_t*)Bv + bz * sBb + (long)nbase * K;
  else
    Bf = (nbase < nsplit) ? ((const float*)Bv  + (long)nbase * K)
                          : ((const float*)Bv2 + (long)(nbase - nsplit) * K);

  const int r4 = t >> 2;                          // staging row 0..63
  const int kq = (t & 3) ^ ((r4 >> 1) & 3);       // XOR-swizzled source k-quad

  f32x4 acc[4][NT];
  #pragma unroll
  for (int i = 0; i < 4; i++)
    #pragma unroll
    for (int j = 0; j < NT; j++) acc[i][j] = (f32x4){0.f, 0.f, 0.f, 0.f};

  const int mrow = lane & 15;
  const int fq   = lane >> 4;
  const int aswz = (fq ^ ((mrow >> 1) & 3)) * 8;  // swizzled frag k-offset (elems)

  for (int k0 = 0; k0 < K; k0 += BK) {
    __syncthreads();
    gload_lds16(Ab + (long)r4 * K + k0 + kq * 8,        (char*)sA + t * 16);
    gload_lds16(Ab + (long)(64 + r4) * K + k0 + kq * 8, (char*)sA + 4096 + t * 16);
    if constexpr (BSRC == 0) {
      gload_lds16(Bb + (long)r4 * K + k0 + kq * 8,        (char*)sB + t * 16);
      if constexpr (BN == 128)
        gload_lds16(Bb + (long)(64 + r4) * K + k0 + kq * 8, (char*)sB + 4096 + t * 16);
    } else {
      {
        f32x4 b0 = *(const f32x4*)(Bf + (long)r4 * K + k0 + kq * 8);
        f32x4 b1 = *(const f32x4*)(Bf + (long)r4 * K + k0 + kq * 8 + 4);
        bf16x8 bb;
        #pragma unroll
        for (int e = 0; e < 4; e++) { bb[e] = (bf16_t)b0[e]; bb[e + 4] = (bf16_t)b1[e]; }
        *(bf16x8*)((char*)sB + t * 16) = bb;
      }
      if constexpr (BN == 128) {
        f32x4 b0 = *(const f32x4*)(Bf + (long)(64 + r4) * K + k0 + kq * 8);
        f32x4 b1 = *(const f32x4*)(Bf + (long)(64 + r4) * K + k0 + kq * 8 + 4);
        bf16x8 bb;
        #pragma unroll
        for (int e = 0; e < 4; e++) { bb[e] = (bf16_t)b0[e]; bb[e + 4] = (bf16_t)b1[e]; }
        *(bf16x8*)((char*)sB + 4096 + t * 16) = bb;
      }
    }
    __syncthreads();

    bf16x8 af[4], bv[NT];
    #pragma unroll
    for (int mt = 0; mt < 4; mt++)
      af[mt] = *(const bf16x8*)(sA + (wm * 64 + mt * 16 + mrow) * 32 + aswz);
    #pragma unroll
    for (int nt = 0; nt < NT; nt++)
      bv[nt] = *(const bf16x8*)(sB + (wn * (BN / 2) + nt * 16 + mrow) * 32 + aswz);
    #pragma unroll
    for (int mt = 0; mt < 4; mt++)
      #pragma unroll
      for (int nt = 0; nt < NT; nt++)
        acc[mt][nt] = __builtin_amdgcn_mfma_f32_16x16x32_bf16(af[mt], bv[nt], acc[mt][nt], 0, 0, 0);
  }

  const int rbase = (lane >> 4) * 4;
  #pragma unroll
  for (int mt = 0; mt < 4; mt++)
    #pragma unroll
    for (int nt = 0; nt < NT; nt++)
      #pragma unroll
      for (int r = 0; r < 4; r++) {
        int grow = blockIdx.x * BM + wm * 64 + mt * 16 + rbase + r;
        int gcol = nbase + wn * (BN / 2) + nt * 16 + (lane & 15);
        if constexpr (EPI == 0) {
          ((bf16_t*)Cv)[bz * sCb + (long)grow * N + gcol] = (bf16_t)acc[mt][nt][r];
        } else {
          ((float*)Cv)[bz * sCb + (long)grow * N + gcol] =
              acc[mt][nt][r] + rowb[bz * M + grow] + colb[bz * N + gcol] + sb[0];
        }
      }
}

// ---------------------------------------------------------------------------
// Recurrent biLSTM stage (R6 protocol, proven). grid = 96: dir(2) x
// slice(24) x bg(2), 512 threads = 8 waves, wave w: gate g = w&3, col-half
// ch = w>>2. whh tile (16 cols) in VGPRs (24 x bf16x8 = 96 VGPR/lane).
// LDS: sH (h staging, 776-elem padded rows) + sG (gate exchange, stride-17).
// Exchange: E dwords {tag:16 | bf16 h:16}, parity double-buffered, relaxed
// AGENT atomics (LLC). Consumers poll data tags directly — no flags, no
// barrier, one LLC trip per step. tag = tagbase + step.
// xg: [B*T, 6144] bf16 (fwd 4H | bwd 4H, gate order i,f,g,o).
// mout: [B, T, 2H] bf16 (fwd | bwd) — plain stores, for downstream kernels.
// ---------------------------------------------------------------------------
__global__ __launch_bounds__(512) void k_lstm(
    const bf16_t* __restrict__ xg, bf16_t* __restrict__ mout,
    unsigned* __restrict__ E,
    const float* __restrict__ whh_f, const float* __restrict__ whh_b,
    const float* __restrict__ bias_f, const float* __restrict__ bias_b,
    int tagbase)
{
  __shared__ bf16_t sH[16 * 776];   // 24,832 B
  __shared__ float  sG[4 * 272];    //  4,352 B => 29,184 B total
  const int t    = threadIdx.x;
  const int lane = t & 63;
  const int w    = t >> 6;                 // wave 0..7
  const int g    = w & 3;                  // gate
  const int ch   = w >> 2;                 // col half (16-col tile)
  const int blk  = blockIdx.x;
  const int dir  = blk / 48;
  const int qq   = blk - dir * 48;
  const int sl   = qq >> 1;                // slice 0..23
  const int bg   = qq & 1;                 // batch group 0..1
  const int j0   = sl * 32;
  const float* whh  = dir ? whh_b : whh_f;
  const float* bias = dir ? bias_b : bias_f;

  const int mrow = lane & 15;
  const int fq   = lane >> 4;

  // stage this wave's whh tile into registers (B operand), f32 -> bf16.
  // lane (mrow,fq) holds whh[g*768 + j0 + ch*16 + mrow][kc*32 + fq*8 .. +8]
  bf16x8 bw[24];
  {
    const float* wrow = whh + (long)(g * 768 + j0 + ch * 16 + mrow) * 768 + fq * 8;
    #pragma unroll
    for (int kc = 0; kc < 24; kc++) {
      f32x4 v0 = *(const f32x4*)(wrow + kc * 32);
      f32x4 v1 = *(const f32x4*)(wrow + kc * 32 + 4);
      bf16x8 bb;
      #pragma unroll
      for (int e = 0; e < 4; e++) { bb[e] = (bf16_t)v0[e]; bb[e + 4] = (bf16_t)v1[e]; }
      bw[kc] = bb;
    }
  }

  const int b16 = t >> 5;                  // local batch 0..15
  const int jj  = t & 31;                  // local col 0..31
  float bsv[4];
  #pragma unroll
  for (int gi = 0; gi < 4; gi++) bsv[gi] = bias[gi * 768 + j0 + jj];

  // loop-invariant consumer offsets: e = i*512+t covers 16 batches x 384 qwords
  int soff[12];
  #pragma unroll
  for (int i = 0; i < 12; i++) {
    int e = i * 512 + t;
    soff[i] = (e / 384) * 1552 + (e % 384) * 4;  // sH byte offset (2 bf16 per qword)
  }

  float cst = 0.f;
  const int aoff0 = mrow * 776 + fq * 8;
  const long xrow0 = (long)(bg * 16 + b16) * TT;

  for (int s = 0; s < TT; s++) {
    const int tc = dir ? (TT - 1 - s) : s;

    if (s == 0) {
      for (int e = t; e < 1552; e += 512)
        *(f32x4*)((char*)sH + e * 16) = (f32x4){0.f, 0.f, 0.f, 0.f};
    } else {
      const unsigned want = (unsigned)(tagbase + s - 1);
      const int par = (s - 1) & 1;
      const ull* src = (const ull*)E + ((long)(par * 2 + dir) * 32 + bg * 16) * 384;
      ull qv[12];
      #pragma unroll
      for (int i = 0; i < 12; i++)
        qv[i] = __hip_atomic_load(src + i * 512 + t, __ATOMIC_RELAXED, __HIP_MEMORY_SCOPE_AGENT);
      for (;;) {
        unsigned bad = 0;
        #pragma unroll
        for (int i = 0; i < 12; i++) {
          unsigned lo = (unsigned)qv[i], hi = (unsigned)(qv[i] >> 32);
          if ((lo >> 16) != want || (hi >> 16) != want) bad |= 1u << i;
        }
        if (!bad) break;
        #pragma unroll
        for (int i = 0; i < 12; i++)
          if (bad & (1u << i))
            qv[i] = __hip_atomic_load(src + i * 512 + t, __ATOMIC_RELAXED, __HIP_MEMORY_SCOPE_AGENT);
      }
      #pragma unroll
      for (int i = 0; i < 12; i++) {
        ushort2 hh;
        hh.x = (unsigned short)qv[i];
        hh.y = (unsigned short)(qv[i] >> 32);
        *(ushort2*)((char*)sH + soff[i]) = hh;
      }
    }

    // xg gate values: issued AFTER the poll (so poll waitcnts never force
    // them) and consumed after MFMA; lgkm-only barriers keep them in flight.
    float xv[4];
    {
      long xr = (xrow0 + tc) * 6144 + dir * 3072 + j0 + jj;
      #pragma unroll
      for (int gi = 0; gi < 4; gi++) xv[gi] = (float)xg[xr + gi * 768];
    }

    wg_barrier_lds();

    // two independent 12-deep accumulate chains over K=768
    f32x4 a0 = (f32x4){0.f, 0.f, 0.f, 0.f};
    f32x4 a1 = (f32x4){0.f, 0.f, 0.f, 0.f};
    #pragma unroll
    for (int kc = 0; kc < 24; kc += 2) {
      bf16x8 av0 = *(const bf16x8*)(sH + aoff0 + kc * 32);
      bf16x8 av1 = *(const bf16x8*)(sH + aoff0 + kc * 32 + 32);
      a0 = __builtin_amdgcn_mfma_f32_16x16x32_bf16(av0, bw[kc],     a0, 0, 0, 0);
      a1 = __builtin_amdgcn_mfma_f32_16x16x32_bf16(av1, bw[kc + 1], a1, 0, 0, 0);
    }
    #pragma unroll
    for (int r = 0; r < 4; r++)
      sG[g * 272 + (ch * 16 + mrow) * 17 + fq * 4 + r] = a0[r] + a1[r];
    wg_barrier_lds();

    {
      float gv0 = sG[0 * 272 + jj * 17 + b16] + xv[0] + bsv[0];
      float gv1 = sG[1 * 272 + jj * 17 + b16] + xv[1] + bsv[1];
      float gv2 = sG[2 * 272 + jj * 17 + b16] + xv[2] + bsv[2];
      float gv3 = sG[3 * 272 + jj * 17 + b16] + xv[3] + bsv[3];
      gv0 = 1.f / (1.f + __expf(-gv0));
      gv1 = 1.f / (1.f + __expf(-gv1));
      gv2 = 1.f - 2.f / (__expf(2.f * gv2) + 1.f);
      gv3 = 1.f / (1.f + __expf(-gv3));
      cst = gv1 * cst + gv0 * gv2;
      float hv = gv3 * (1.f - 2.f / (__expf(2.f * cst) + 1.f));
      union { bf16_t b; unsigned short u; } pk;
      pk.b = (bf16_t)hv;
      unsigned tag = (unsigned)(tagbase + s);
      long ed = ((long)((s & 1) * 2 + dir) * 32 + bg * 16 + b16) * 768 + j0 + jj;
      __hip_atomic_store(E + ed, (tag << 16) | pk.u,
                         __ATOMIC_RELAXED, __HIP_MEMORY_SCOPE_AGENT);
      mout[(xrow0 + tc) * 1536 + dir * 768 + j0 + jj] = pk.b;
    }
    // no end-of-step barrier: next iteration's sH overwrite is fenced by the
    // first wg_barrier (all threads passed MFMA sH reads by then)
  }
}

// --------------------------- attention helpers -----------------------------

__global__ __launch_bounds__(256) void k_pack(
    const float* __restrict__ c, const float* __restrict__ q,
    const float* __restrict__ wcq, bf16_t* __restrict__ cw, bf16_t* __restrict__ qb)
{
  int i = blockIdx.x * 256 + threadIdx.x;        // 43008 blocks -> 11,010,048
  if (i < 9437184) {
    int h = i % 768;
    cw[i] = (bf16_t)(c[i] * wcq[h]);
  } else {
    int j = i - 9437184;
    qb[j] = (bf16_t)q[j];
  }
}

__global__ __launch_bounds__(256) void k_proj(
    const float* __restrict__ c, const float* __restrict__ q,
    const float* __restrict__ wc, const float* __restrict__ bc,
    const float* __restrict__ wq, const float* __restrict__ bq,
    float* __restrict__ projc, float* __restrict__ projq)
{
  int row  = blockIdx.x * 4 + (threadIdx.x >> 6);  // 0..14335
  int lane = threadIdx.x & 63;
  const float *src, *w;
  bool isC = row < 12288;
  if (isC) { src = c + (long)row * 768;          w = wc; }
  else     { src = q + (long)(row - 12288) * 768; w = wq; }
  float a = 0.f;
  for (int k = lane * 4; k < 768; k += 256) {
    f32x4 v = *(const f32x4*)(src + k);
    f32x4 wv = *(const f32x4*)(w + k);
    a += v[0]*wv[0] + v[1]*wv[1] + v[2]*wv[2] + v[3]*wv[3];
  }
  for (int m = 32; m; m >>= 1) a += __shfl_xor(a, m);
  if (lane == 0) {
    if (isC) projc[row] = a + bc[0];
    else     projq[row - 12288] = a + bq[0];
  }
}

__global__ __launch_bounds__(256) void k_smax_j(
    const float* __restrict__ s, bf16_t* __restrict__ a, float* __restrict__ smax)
{
  int row  = blockIdx.x * 4 + (threadIdx.x >> 6);
  int lane = threadIdx.x & 63;
  float v = s[(long)row * 64 + lane];
  float mx = v;
  for (int m = 32; m; m >>= 1) mx = fmaxf(mx, __shfl_xor(mx, m));
  float p = __expf(v - mx);
  float sum = p;
  for (int m = 32; m; m >>= 1) sum += __shfl_xor(sum, m);
  a[(long)row * 64 + lane] = (bf16_t)(p / sum);
  if (lane == 0) smax[row] = mx;
}

__global__ __launch_bounds__(384) void k_smax_i(
    const float* __restrict__ smax, float* __restrict__ bw)
{
  __shared__ float red[8];
  int b = blockIdx.x, t = threadIdx.x;   // 384 threads, 6 waves
  int lane = t & 63, wv = t >> 6;
  float v = smax[b * 384 + t];
  float mx = v;
  for (int m = 32; m; m >>= 1) mx = fmaxf(mx, __shfl_xor(mx, m));
  if (lane == 0) red[wv] = mx;
  __syncthreads();
  float gm = red[0];
  #pragma unroll
  for (int i = 1; i < 6; i++) gm = fmaxf(gm, red[i]);
  float p = __expf(v - gm);
  float sm = p;
  for (int m = 32; m; m >>= 1) sm += __shfl_xor(sm, m);
  __syncthreads();
  if (lane == 0) red[wv] = sm;
  __syncthreads();
  float tot = red[0];
  #pragma unroll
  for (int i = 1; i < 6; i++) tot += red[i];
  bw[b * 384 + t] = p / tot;
}

__global__ __launch_bounds__(256) void k_q2c(
    const float* __restrict__ bw, const float* __restrict__ c, float* __restrict__ q2c)
{
  int b = blockIdx.y;
  int h = blockIdx.x * 256 + threadIdx.x;
  const float* cb = c + (long)b * 384 * 768;
  float acc = 0.f;
  for (int i = 0; i < 384; i++) acc += bw[b * 384 + i] * cb[(long)i * 768 + h];
  q2c[b * 768 + h] = acc;
}

__global__ __launch_bounds__(256) void k_tq(
    const bf16_t* __restrict__ qb, bf16_t* __restrict__ qT)
{
  __shared__ bf16_t sT[64][72];
  int b = blockIdx.y, hc = blockIdx.x, t = threadIdx.x;
  {
    int j = t >> 2, h0 = (t & 3) * 16;
    const bf16_t* src = qb + (long)(b * 64 + j) * 768 + hc * 64 + h0;
    *(bf16x8*)&sT[j][h0]     = *(const bf16x8*)(src);
    *(bf16x8*)&sT[j][h0 + 8] = *(const bf16x8*)(src + 8);
  }
  __syncthreads();
  {
    int h = t >> 2, j0 = (t & 3) * 16;
    bf16x8 o0, o1;
    #pragma unroll
    for (int e = 0; e < 8; e++) { o0[e] = sT[j0 + e][h]; o1[e] = sT[j0 + 8 + e][h]; }
    bf16_t* dst = qT + (long)(b * 768 + hc * 64 + h) * 64 + j0;
    *(bf16x8*)dst       = o0;
    *(bf16x8*)(dst + 8) = o1;
  }
}

__global__ __launch_bounds__(256) void k_buildg(
    const float* __restrict__ c, const bf16_t* __restrict__ c2q,
    const float* __restrict__ q2c, bf16_t* __restrict__ g)
{
  int i = blockIdx.x * 256 + threadIdx.x;   // < 9,437,184
  int h = i % 768;
  int row = i / 768;
  int b = row / 384;
  float cv  = c[i];
  float cqv = (float)c2q[i];
  float qcv = q2c[b * 768 + h];
  bf16_t* gr = g + (long)row * 3072;
  gr[h]        = (bf16_t)cv;
  gr[768 + h]  = c2q[i];
  gr[1536 + h] = (bf16_t)(cv * cqv);
  gr[2304 + h] = (bf16_t)(cv * qcv);
}

// heads: g-part (both p1 and p2), one pass over g
__global__ __launch_bounds__(256) void k_headsg(
    const bf16_t* __restrict__ g, const float* __restrict__ w1, const float* __restrict__ w2,
    float* __restrict__ pg1, float* __restrict__ pg2)
{
  int row  = blockIdx.x * 4 + (threadIdx.x >> 6);  // 0..12287
  int lane = threadIdx.x & 63;
  float a1 = 0.f, a2 = 0.f;
  const bf16_t* gr = g + (long)row * 3072;
  for (int k = lane * 8; k < 3072; k += 512) {
    bf16x8 v = *(const bf16x8*)(gr + k);
    f32x4 wa = *(const f32x4*)(w1 + k), wb = *(const f32x4*)(w1 + k + 4);
    f32x4 xa = *(const f32x4*)(w2 + k), xb = *(const f32x4*)(w2 + k + 4);
    #pragma unroll
    for (int e = 0; e < 4; e++) {
      a1 += (float)v[e] * wa[e] + (float)v[e + 4] * wb[e];
      a2 += (float)v[e] * xa[e] + (float)v[e + 4] * xb[e];
    }
  }
  for (int m_ = 32; m_; m_ >>= 1) { a1 += __shfl_xor(a1, m_); a2 += __shfl_xor(a2, m_); }
  if (lane == 0) { pg1[row] = a1; pg2[row] = a2; }
}

// heads: m-part, writes final output rows
__global__ __launch_bounds__(256) void k_headsm(
    const bf16_t* __restrict__ m, const float* __restrict__ wm,
    const float* __restrict__ pg, const float* __restrict__ bg,
    const float* __restrict__ bm, float* __restrict__ out)
{
  int row  = blockIdx.x * 4 + (threadIdx.x >> 6);  // 0..12287
  int lane = threadIdx.x & 63;
  float a = 0.f;
  const bf16_t* mr = m + (long)row * 1536;
  for (int k = lane * 8; k < 1536; k += 512) {
    bf16x8 v = *(const bf16x8*)(mr + k);
    f32x4 wa = *(const f32x4*)(wm + k), wb = *(const f32x4*)(wm + k + 4);
    #pragma unroll
    for (int e = 0; e < 4; e++) a += (float)v[e] * wa[e] + (float)v[e + 4] * wb[e];
  }
  for (int m_ = 32; m_; m_ >>= 1) a += __shfl_xor(a, m_);
  if (lane == 0) out[row] = pg[row] + a + bg[0] + bm[0];
}

// ---------------------------------------------------------------------------

extern "C" void kernel_launch(void* const* d_in, const int* in_sizes, int n_in,
                              void* d_out, int out_size, void* d_ws, size_t ws_size,
                              hipStream_t stream)
{
  (void)in_sizes; (void)n_in; (void)out_size;
  const float* c    = (const float*)d_in[0];
  const float* q    = (const float*)d_in[1];
  const float* wac  = (const float*)d_in[2];
  const float* bac  = (const float*)d_in[3];
  const float* waq  = (const float*)d_in[4];
  const float* baq  = (const float*)d_in[5];
  const float* wacq = (const float*)d_in[6];
  const float* bacq = (const float*)d_in[7];
  const float* l1f_wih = (const float*)d_in[8];
  const float* l1f_whh = (const float*)d_in[9];
  const float* l1f_b   = (const float*)d_in[10];
  const float* l1b_wih = (const float*)d_in[11];
  const float* l1b_whh = (const float*)d_in[12];
  const float* l1b_b   = (const float*)d_in[13];
  const float* l2f_wih = (const float*)d_in[14];
  const float* l2f_whh = (const float*)d_in[15];
  const float* l2f_b   = (const float*)d_in[16];
  const float* l2b_wih = (const float*)d_in[17];
  const float* l2b_whh = (const float*)d_in[18];
  const float* l2b_b   = (const float*)d_in[19];
  const float* lof_wih = (const float*)d_in[20];
  const float* lof_whh = (const float*)d_in[21];
  const float* lof_b   = (const float*)d_in[22];
  const float* lob_wih = (const float*)d_in[23];
  const float* lob_whh = (const float*)d_in[24];
  const float* lob_b   = (const float*)d_in[25];
  const float* p1wg = (const float*)d_in[26];
  const float* p1bg = (const float*)d_in[27];
  const float* p1wm = (const float*)d_in[28];
  const float* p1bm = (const float*)d_in[29];
  const float* p2wg = (const float*)d_in[30];
  const float* p2bg = (const float*)d_in[31];
  const float* p2wm = (const float*)d_in[32];
  const float* p2bm = (const float*)d_in[33];

  // workspace layout (total ~227.6 MB)
  char* ws = (char*)d_ws;
  bf16_t* g_bf = (bf16_t*)ws;                       // [0, 75.5MB) g
  bf16_t* mA   = (bf16_t*)ws;                       // aliases g (g dead by stage1 lstm)
  bf16_t* mB   = (bf16_t*)(ws + 37748736L);         // second half of g region
  bf16_t* m2   = (bf16_t*)ws;                       // aliases mA (dead after stage2 GEMM)
  char*   xgc  = ws + 75497472L;                    // [75.5MB, 226.5MB) xg
  bf16_t* xg   = (bf16_t*)xgc;
  // attention temps alias the xg region (dead before stage1 GEMM writes xg)
  bf16_t* cw  = (bf16_t*)xgc;                       // 18,874,368
  bf16_t* qb  = (bf16_t*)(xgc + 18874368L);         //  3,145,728
  bf16_t* qT  = (bf16_t*)(xgc + 22020096L);         //  3,145,728
  float*  sS  = (float*) (xgc + 25165824L);         //  3,145,728
  bf16_t* aP  = (bf16_t*)(xgc + 28311552L);         //  1,572,864
  bf16_t* c2q = (bf16_t*)(xgc + 29884416L);         // 18,874,368
  char* tail = ws + 226492416L;
  float*    projc = (float*)tail;                   // 49,152
  float*    projq = (float*)(tail + 49152);         //  8,192
  float*    smax  = (float*)(tail + 57344);         // 49,152
  float*    bw    = (float*)(tail + 106496);        // 49,152
  float*    q2c   = (float*)(tail + 155648);        // 98,304
  float*    pg1   = (float*)(tail + 253952);        // 49,152
  float*    pg2   = (float*)(tail + 303104);        // 49,152
  unsigned* E     = (unsigned*)(tail + 352256);     // 2par x 2dir x 32 x 768 x 4B = 786,432
  // transient bf16 B matrices for stage GEMMs (windows dead at time of use):
  bf16_t* B2 = mB;                                  // [37.7, 56.6MB) free during stage-2 GEMM
  bf16_t* B3 = (bf16_t*)ws;                         // [0, 18.9MB)    free during stage-3 GEMM
  // stage-1 B (37.7MB) only if workspace extends past the tail:
  bool   big = ws_size >= 265428992UL;
  bf16_t* B1 = big ? (bf16_t*)(ws + 227680256L) : nullptr;

  k_zeroE<<<768, 256, 0, stream>>>(E);

  // ---- attention ----
  k_pack<<<43008, 256, 0, stream>>>(c, q, wacq, cw, qb);
  k_proj<<<3584, 256, 0, stream>>>(c, q, wac, bac, waq, baq, projc, projq);
  k_gemm<64,1,0><<<dim3(3,1,32), 256, 0, stream>>>(cw, qb, nullptr, 1<<30, sS,
      384, 64, 768, (long)384*768, (long)64*768, (long)384*64, projc, projq, bacq);
  k_smax_j<<<3072, 256, 0, stream>>>(sS, aP, smax);
  k_smax_i<<<32, 384, 0, stream>>>(smax, bw);
  k_q2c<<<dim3(3,32), 256, 0, stream>>>(bw, c, q2c);
  k_tq<<<dim3(12,32), 256, 0, stream>>>(qb, qT);
  k_gemm<64,0,0><<<dim3(3,12,32), 256, 0, stream>>>(aP, qT, nullptr, 1<<30, c2q,
      384, 768, 64, (long)384*64, (long)768*64, (long)384*768, nullptr, nullptr, nullptr);
  k_buildg<<<36864, 256, 0, stream>>>(c, c2q, q2c, g_bf);
  k_headsg<<<3072, 256, 0, stream>>>(g_bf, p1wg, p2wg, pg1, pg2);

  // ---- stage 1 (input 4H=3072) ----
  if (big) {
    k_cvtB<<<18432, 256, 0, stream>>>(l1f_wih, l1b_wih, 3072L * 3072, B1);
    k_gemm<128,0,0><<<dim3(96,48,1), 256, 0, stream>>>(g_bf, B1, nullptr, 1<<30, xg,
        12288, 6144, 3072, 0, 0, 0, nullptr, nullptr, nullptr);
  } else {
    k_gemm<128,0,1><<<dim3(96,48,1), 256, 0, stream>>>(g_bf, l1f_wih, l1b_wih, 3072, xg,
        12288, 6144, 3072, 0, 0, 0, nullptr, nullptr, nullptr);
  }
  k_lstm<<<96, 512, 0, stream>>>(xg, mA, E, l1f_whh, l1b_whh, l1f_b, l1b_b, 0);

  // ---- stage 2 (input 2H=1536) ----
  // B2 occupies the mB slot, which is dead until stage-2 k_lstm writes mB.
  k_cvtB<<<9216, 256, 0, stream>>>(l2f_wih, l2b_wih, 3072L * 1536, B2);
  k_gemm<128,0,0><<<dim3(96,48,1), 256, 0, stream>>>(mA, B2, nullptr, 1<<30, xg,
      12288, 6144, 1536, 0, 0, 0, nullptr, nullptr, nullptr);
  k_lstm<<<96, 512, 0, stream>>>(xg, mB, E, l2f_whh, l2b_whh, l2f_b, l2b_b, 384);
  k_headsm<<<3072, 256, 0, stream>>>(mB, p1wm, pg1, p1bg, p1bm, (float*)d_out);

  // ---- stage 3 (output LSTM, input 2H=1536) ----
  // B3 occupies the mA/m2 slot, dead after the stage-2 GEMM consumed mA and
  // until stage-3 k_lstm writes m2.
  k_cvtB<<<9216, 256, 0, stream>>>(lof_wih, lob_wih, 3072L * 1536, B3);
  k_gemm<128,0,0><<<dim3(96,48,1), 256, 0, stream>>>(mB, B3, nullptr, 1<<30, xg,
      12288, 6144, 1536, 0, 0, 0, nullptr, nullptr, nullptr);
  k_lstm<<<96, 512, 0, stream>>>(xg, m2, E, lof_whh, lob_whh, lof_b, lob_b, 768);
  k_headsm<<<3072, 256, 0, stream>>>(m2, p2wm, pg2, p2bg, p2bm, (float*)d_out + 12288);
}